// Round 13
// baseline (261.816 us; speedup 1.0000x reference)
//
#include <hip/hip_runtime.h>
#include <math.h>

#define HW 262144     // 512*512
#define NIMG 96       // B*C
#define NQBIN 4096

typedef __attribute__((ext_vector_type(8))) short bf16x8;
typedef __attribute__((ext_vector_type(4))) float f32x4;

// ---- helpers ----
__device__ __forceinline__ unsigned fmap_u(float f){
  unsigned u = __float_as_uint(f);
  return (u & 0x80000000u) ? ~u : (u | 0x80000000u);
}
__device__ __forceinline__ float funmap_u(unsigned u){
  unsigned v = (u & 0x80000000u) ? (u & 0x7fffffffu) : ~u;
  return __uint_as_float(v);
}
__device__ __forceinline__ unsigned bf16rne(float f){
  unsigned u = __float_as_uint(f);
  return (u + 0x7fffu + ((u >> 16) & 1u)) >> 16;
}

// global -> LDS direct DMA, 16 B per lane. LDS dest = wave-uniform base + lane*16.
typedef __attribute__((address_space(3))) unsigned lds_u;
typedef const __attribute__((address_space(1))) unsigned glb_u;
__device__ __forceinline__ void gll16(const void* g, void* l){
  __builtin_amdgcn_global_load_lds((glb_u*)g, (lds_u*)l, 16, 0, 0);
}

// ---- Dir[n] = Re( ifft(filter_map row 0) )[n], computed in double ----
__global__ void k_dir(const float* __restrict__ fmap_in, float* __restrict__ Dir){
  int n = blockIdx.x;
  int t = threadIdx.x;
  double s = 0.0;
  for(int c = t; c < 512; c += 256){
    int a = (c * n) & 511;
    s += (double)fmap_in[c] * cos(6.283185307179586476925287 * (double)a / 512.0);
  }
  __shared__ double red[256];
  red[t] = s; __syncthreads();
  for(int off = 128; off; off >>= 1){
    if(t < off) red[t] += red[t + off];
    __syncthreads();
  }
  if(t == 0) Dir[n] = (float)(red[0] / 512.0);
}

// ---- Cm[a][b] = bf16( Dir[(a-b)&511] )  (512 KB, L2-resident) ----
__global__ void k_cmat(const float* __restrict__ Dir, unsigned short* __restrict__ CmH){
  int a = blockIdx.x;
  for(int b = threadIdx.x; b < 512; b += 256){
    float d = Dir[(a - b) & 511];
    CmH[(size_t)a * 512 + b] = (unsigned short)bf16rne(d);
  }
}

// ==== exact-to-24-bits median via 2-pass LDS radix select (12 / 12 bits) ====
__global__ __launch_bounds__(256) void k_p1(const float* __restrict__ x, unsigned* __restrict__ h){
  __shared__ unsigned sh[4096];
  const int img  = blockIdx.x >> 3;
  const int part = blockIdx.x & 7;
  const float4* p = (const float4*)(x + (size_t)img * HW + (size_t)part * 32768);
  for(int i = threadIdx.x; i < 4096; i += 256) sh[i] = 0;
  __syncthreads();
  for(int i = threadIdx.x; i < 8192; i += 256){
    float4 v = p[i];
    atomicAdd(&sh[fmap_u(v.x) >> 20], 1u);
    atomicAdd(&sh[fmap_u(v.y) >> 20], 1u);
    atomicAdd(&sh[fmap_u(v.z) >> 20], 1u);
    atomicAdd(&sh[fmap_u(v.w) >> 20], 1u);
  }
  __syncthreads();
  unsigned* hh = h + (size_t)img * 4096;
  for(int i = threadIdx.x; i < 4096; i += 256){
    unsigned c = sh[i];
    if(c) atomicAdd(&hh[i], c);
  }
}

__global__ __launch_bounds__(256) void k_p2(const float* __restrict__ x, const uint2* __restrict__ sel1,
                                            unsigned* __restrict__ h){
  __shared__ unsigned sh[4096];
  const int img  = blockIdx.x >> 3;
  const int part = blockIdx.x & 7;
  const unsigned b1 = sel1[img].x;
  const float4* p = (const float4*)(x + (size_t)img * HW + (size_t)part * 32768);
  for(int i = threadIdx.x; i < 4096; i += 256) sh[i] = 0;
  __syncthreads();
  for(int i = threadIdx.x; i < 8192; i += 256){
    float4 v = p[i];
    unsigned u;
    u = fmap_u(v.x); if((u >> 20) == b1) atomicAdd(&sh[(u >> 8) & 0xFFFu], 1u);
    u = fmap_u(v.y); if((u >> 20) == b1) atomicAdd(&sh[(u >> 8) & 0xFFFu], 1u);
    u = fmap_u(v.z); if((u >> 20) == b1) atomicAdd(&sh[(u >> 8) & 0xFFFu], 1u);
    u = fmap_u(v.w); if((u >> 20) == b1) atomicAdd(&sh[(u >> 8) & 0xFFFu], 1u);
  }
  __syncthreads();
  unsigned* hh = h + (size_t)img * 4096;
  for(int i = threadIdx.x; i < 4096; i += 256){
    unsigned c = sh[i];
    if(c) atomicAdd(&hh[i], c);
  }
}

__global__ void k_scan1(const unsigned* __restrict__ h, uint2* __restrict__ osel){
  int img = blockIdx.x, t = threadIdx.x;
  const unsigned* hh = h + (size_t)img * 4096;
  __shared__ unsigned csum[256];
  unsigned s = 0;
  for(int j = 0; j < 16; j++) s += hh[t * 16 + j];
  csum[t] = s; __syncthreads();
  if(t == 0){
    unsigned k = 131071u, cum = 0; int chunk = 0;
    for(; chunk < 256; ++chunk){ if(cum + csum[chunk] > k) break; cum += csum[chunk]; }
    int b = chunk * 16;
    for(;; ++b){ unsigned c = hh[b]; if(cum + c > k) break; cum += c; }
    osel[img] = make_uint2((unsigned)b, k - cum);
  }
}

__global__ void k_scan_med(const unsigned* __restrict__ h, const uint2* __restrict__ sel1,
                           float* __restrict__ med){
  int img = blockIdx.x, t = threadIdx.x;
  const unsigned* hh = h + (size_t)img * 4096;
  __shared__ unsigned csum[256];
  unsigned s = 0;
  for(int j = 0; j < 16; j++) s += hh[t * 16 + j];
  csum[t] = s; __syncthreads();
  if(t == 0){
    unsigned k = sel1[img].y, cum = 0; int chunk = 0;
    for(; chunk < 256; ++chunk){ if(cum + csum[chunk] > k) break; cum += csum[chunk]; }
    int b = chunk * 16;
    for(;; ++b){ unsigned c = hh[b]; if(cum + c > k) break; cum += c; }
    unsigned u = (sel1[img].x << 20) | ((unsigned)b << 8) | 128u;
    med[img] = funmap_u(u) + 0.2f;
  }
}

// ==== MFMA row pass: 2-deep A-prefetch (two named regsets) + DMA B, counted vmcnt ====
// t1T[img][n][h] = bf16( sum_k (mask?x:med)[r][k] * Cm[n][k] )
__global__ __launch_bounds__(512, 4) void k_rowpass(
    const float* __restrict__ x, const float* __restrict__ mask,
    const float* __restrict__ med,
    const unsigned short* __restrict__ CmH,
    unsigned short* __restrict__ t1h)
{
  __shared__ __align__(16) unsigned short As [2][8192];
  __shared__ __align__(16) unsigned short BsH[2][8192];

  // XCD swizzle: 4 sibling n-blocks (same x rows) on the same XCD
  const int b    = blockIdx.x;           // 0..1535
  const int xcd  = b & 7;
  const int i8   = b >> 3;               // 0..191
  const int rblk = xcd * 48 + (i8 >> 2); // 0..383
  const int nblk = i8 & 3;
  const int r0 = rblk * 128;
  const int n0 = nblk * 128;
  const int bc = r0 >> 9;
  const int bb = bc / 3;
  const float mv = med[bc];

  const int t    = threadIdx.x;
  const int lane = t & 63;
  const int wv   = t >> 6;               // 0..7
  const int wm   = (wv >> 2) * 64;
  const int wn   = (wv & 3) * 32;
  const int fr   = lane & 15;
  const int fg   = lane >> 4;
  const int sw   = lane & 7;

  // A reg-staging: thread -> row t>>2, 16 cols at (t&3)*16
  const int srow = t >> 2;
  const int sc   = (t & 3) << 4;
  const float* xr = x    + ((size_t)(r0 + srow) << 9) + sc;
  const float* mr = mask + (size_t)bb * HW + ((size_t)((r0 + srow) & 511) << 9) + sc;

  // B DMA mapping
  const int drow = lane >> 3;
  const int dblk = (lane & 7) ^ drow;
  const unsigned short* bhsrc = CmH + ((size_t)(n0 + wv*8 + drow) << 9) + dblk * 8;
  const int dbase = wv * 8 * 64;

  f32x4 acc[4][2];
  #pragma unroll
  for(int i = 0; i < 4; i++)
    #pragma unroll
    for(int j = 0; j < 2; j++) acc[i][j] = (f32x4){0.f, 0.f, 0.f, 0.f};

  // two named A register sets (static indexing; tile t lives in set t&1)
  float4 px0[4], pm0[4], px1[4], pm1[4];

  auto ALOAD0 = [&](int k0){
    #pragma unroll
    for(int q = 0; q < 4; q++){
      px0[q] = *(const float4*)(xr + k0 + q * 4);
      pm0[q] = *(const float4*)(mr + k0 + q * 4);
    }
  };
  auto ALOAD1 = [&](int k0){
    #pragma unroll
    for(int q = 0; q < 4; q++){
      px1[q] = *(const float4*)(xr + k0 + q * 4);
      pm1[q] = *(const float4*)(mr + k0 + q * 4);
    }
  };
  auto BDMA = [&](int buf, int k0){
    #pragma unroll
    for(int q = 0; q < 2; q++){
      const size_t so = ((size_t)(q * 64) << 9) + k0;
      const int    dq = dbase + q * 4096;
      gll16(bhsrc + so, &BsH[buf][dq]);
    }
  };
  auto ACONV0 = [&](int buf){
    unsigned hp[8];
    #pragma unroll
    for(int q = 0; q < 4; q++){
      unsigned h0 = bf16rne((pm0[q].x != 0.f) ? px0[q].x : mv);
      unsigned h1 = bf16rne((pm0[q].y != 0.f) ? px0[q].y : mv);
      unsigned h2 = bf16rne((pm0[q].z != 0.f) ? px0[q].z : mv);
      unsigned h3 = bf16rne((pm0[q].w != 0.f) ? px0[q].w : mv);
      hp[q*2]   = (h1 << 16) | h0;
      hp[q*2+1] = (h3 << 16) | h2;
    }
    const int b0 = (t & 3) * 2;
    *(uint4*)&As[buf][srow * 64 + (( b0      ^ (srow & 7)) << 3)] = make_uint4(hp[0], hp[1], hp[2], hp[3]);
    *(uint4*)&As[buf][srow * 64 + (((b0 | 1) ^ (srow & 7)) << 3)] = make_uint4(hp[4], hp[5], hp[6], hp[7]);
  };
  auto ACONV1 = [&](int buf){
    unsigned hp[8];
    #pragma unroll
    for(int q = 0; q < 4; q++){
      unsigned h0 = bf16rne((pm1[q].x != 0.f) ? px1[q].x : mv);
      unsigned h1 = bf16rne((pm1[q].y != 0.f) ? px1[q].y : mv);
      unsigned h2 = bf16rne((pm1[q].z != 0.f) ? px1[q].z : mv);
      unsigned h3 = bf16rne((pm1[q].w != 0.f) ? px1[q].w : mv);
      hp[q*2]   = (h1 << 16) | h0;
      hp[q*2+1] = (h3 << 16) | h2;
    }
    const int b0 = (t & 3) * 2;
    *(uint4*)&As[buf][srow * 64 + (( b0      ^ (srow & 7)) << 3)] = make_uint4(hp[0], hp[1], hp[2], hp[3]);
    *(uint4*)&As[buf][srow * 64 + (((b0 | 1) ^ (srow & 7)) << 3)] = make_uint4(hp[4], hp[5], hp[6], hp[7]);
  };
  auto COMPUTE = [&](int buf){
    bf16x8 af[4][2], bh[2][2];
    #pragma unroll
    for(int i = 0; i < 4; i++)
      #pragma unroll
      for(int kq = 0; kq < 2; kq++){
        int row = wm + i*16 + fr;
        af[i][kq] = *(const bf16x8*)&As[buf][row*64 + (((kq*4 + fg) ^ sw) << 3)];
      }
    #pragma unroll
    for(int j = 0; j < 2; j++)
      #pragma unroll
      for(int kq = 0; kq < 2; kq++){
        int row = wn + j*16 + fr;
        bh[j][kq] = *(const bf16x8*)&BsH[buf][row*64 + (((kq*4 + fg) ^ sw) << 3)];
      }
    __builtin_amdgcn_s_setprio(1);
    #pragma unroll
    for(int i = 0; i < 4; i++)
      #pragma unroll
      for(int j = 0; j < 2; j++){
        acc[i][j] = __builtin_amdgcn_mfma_f32_16x16x32_bf16(af[i][0], bh[j][0], acc[i][j], 0, 0, 0);
        acc[i][j] = __builtin_amdgcn_mfma_f32_16x16x32_bf16(af[i][1], bh[j][1], acc[i][j], 0, 0, 0);
      }
    __builtin_amdgcn_s_setprio(0);
  };

  // prologue: tiles 0,1 A-loaded; tile0 B-DMA'd and converted
  ALOAD0(0);                                     // 8 ops  (tile0 -> set0)
  ALOAD1(64);                                    // 8 ops  (tile1 -> set1)
  BDMA(0, 0);                                    // 2 ops
  asm volatile("s_waitcnt vmcnt(10)" ::: "memory");   // tile0 A landed
  ACONV0(0);
  asm volatile("s_waitcnt vmcnt(8)" ::: "memory");    // tile0 B landed (tile1 A in flight)
  asm volatile("s_waitcnt lgkmcnt(0)" ::: "memory");
  __builtin_amdgcn_sched_barrier(0);
  __builtin_amdgcn_s_barrier();

  // steady: compute tile it; stage tile it+1 (B now, A landed last iter); prefetch A(it+2)
  #pragma unroll
  for(int it = 0; it < 6; ++it){
    BDMA((it + 1) & 1, (it + 1) * 64);           // 2 ops
    if((it & 1) == 0) ALOAD0((it + 2) * 64);     // 8 ops  (tile it+2 -> set it&1)
    else              ALOAD1((it + 2) * 64);
    COMPUTE(it & 1);
    asm volatile("s_waitcnt vmcnt(10)" ::: "memory");  // A(it+1) landed; A(it+2)+B(it+1) fly
    if(((it + 1) & 1) == 0) ACONV0((it + 1) & 1);
    else                    ACONV1((it + 1) & 1);
    asm volatile("s_waitcnt vmcnt(8)" ::: "memory");   // B(it+1) landed; A(it+2) crosses barrier
    asm volatile("s_waitcnt lgkmcnt(0)" ::: "memory");
    __builtin_amdgcn_sched_barrier(0);
    __builtin_amdgcn_s_barrier();
  }
  // it = 6: compute tile6; stage tile7 (A in set1 from it=5)
  BDMA(1, 7 * 64);
  COMPUTE(0);
  asm volatile("s_waitcnt vmcnt(2)" ::: "memory");     // A7 landed
  ACONV1(1);
  asm volatile("s_waitcnt vmcnt(0) lgkmcnt(0)" ::: "memory");
  __builtin_amdgcn_sched_barrier(0);
  __builtin_amdgcn_s_barrier();
  COMPUTE(1);                                          // tile7

  // epilogue: t1 transposed single bf16
  const int img = r0 >> 9;
  const int hb  = r0 & 511;
  #pragma unroll
  for(int i = 0; i < 4; i++)
    #pragma unroll
    for(int j = 0; j < 2; j++){
      f32x4 a = acc[i][j];
      unsigned b0 = bf16rne(a[0]), b1 = bf16rne(a[1]), b2 = bf16rne(a[2]), b3 = bf16rne(a[3]);
      int n = n0 + wn + j*16 + fr;
      int h = hb + wm + i*16 + fg*4;
      *(uint2*)&t1h[(size_t)img * HW + ((size_t)n << 9) + h] =
          make_uint2((b1<<16)|b0, (b3<<16)|b2);
    }
}

// ==== MFMA col pass: single-bf16 A (CmH), 64 KB LDS -> 2 blocks/CU; fused q-hist ====
__global__ __launch_bounds__(512, 4) void k_colpass(
    const unsigned short* __restrict__ t1h,
    const unsigned short* __restrict__ CmH,
    float* __restrict__ res, unsigned* __restrict__ qh)
{
  __shared__ __align__(16) unsigned short AsH[2][8192];
  __shared__ __align__(16) unsigned short Bs [2][8192];

  // XCD swizzle: all 16 blocks of one image on the same XCD (t1 image L2-resident)
  const int b    = blockIdx.x;           // 0..1535
  const int xcd  = b & 7;
  const int i8   = b >> 3;               // 0..191
  const int img  = xcd * 12 + (i8 >> 4);
  const int r16  = i8 & 15;
  const int hp0  = (r16 >> 2) * 128;
  const int w0   = (r16 & 3) * 128;

  const int t    = threadIdx.x;
  const int lane = t & 63;
  const int wv   = t >> 6;
  const int wm   = (wv >> 2) * 64;
  const int wn   = (wv & 3) * 32;
  const int fr   = lane & 15;
  const int fg   = lane >> 4;
  const int sw   = lane & 7;

  const int drow = lane >> 3;
  const int dblk = (lane & 7) ^ drow;
  const unsigned short* ahsrc = CmH + ((size_t)(hp0 + wv*8 + drow) << 9) + dblk * 8;
  const unsigned short* bsrc  = t1h + (size_t)img * HW + ((size_t)(w0 + wv*8 + drow) << 9) + dblk * 8;
  const int dbase = wv * 8 * 64;

  f32x4 acc[4][2];
  #pragma unroll
  for(int i = 0; i < 4; i++)
    #pragma unroll
    for(int j = 0; j < 2; j++) acc[i][j] = (f32x4){0.f, 0.f, 0.f, 0.f};

  auto STAGE = [&](int buf, int k0){
    #pragma unroll
    for(int q = 0; q < 2; q++){
      const size_t so = ((size_t)(q * 64) << 9) + k0;
      const int    dq = dbase + q * 4096;
      gll16(ahsrc + so, &AsH[buf][dq]);
      gll16(bsrc  + so, &Bs [buf][dq]);
    }
  };
  auto COMPUTE = [&](int buf){
    bf16x8 ah[4][2], bv[2][2];
    #pragma unroll
    for(int i = 0; i < 4; i++)
      #pragma unroll
      for(int kq = 0; kq < 2; kq++){
        int row = wm + i*16 + fr;
        ah[i][kq] = *(const bf16x8*)&AsH[buf][row*64 + (((kq*4 + fg) ^ sw) << 3)];
      }
    #pragma unroll
    for(int j = 0; j < 2; j++)
      #pragma unroll
      for(int kq = 0; kq < 2; kq++){
        int row = wn + j*16 + fr;
        bv[j][kq] = *(const bf16x8*)&Bs[buf][row*64 + (((kq*4 + fg) ^ sw) << 3)];
      }
    __builtin_amdgcn_s_setprio(1);
    #pragma unroll
    for(int i = 0; i < 4; i++)
      #pragma unroll
      for(int j = 0; j < 2; j++){
        acc[i][j] = __builtin_amdgcn_mfma_f32_16x16x32_bf16(ah[i][0], bv[j][0], acc[i][j], 0, 0, 0);
        acc[i][j] = __builtin_amdgcn_mfma_f32_16x16x32_bf16(ah[i][1], bv[j][1], acc[i][j], 0, 0, 0);
      }
    __builtin_amdgcn_s_setprio(0);
  };

  STAGE(0, 0);
  asm volatile("s_waitcnt vmcnt(0)" ::: "memory");
  __builtin_amdgcn_s_barrier();
  #pragma unroll
  for(int it = 0; it < 7; ++it){
    STAGE((it + 1) & 1, (it + 1) * 64);
    asm volatile("s_waitcnt vmcnt(4)" ::: "memory");   // drain tile it, keep it+1 in flight
    __builtin_amdgcn_s_barrier();
    COMPUTE(it & 1);
    asm volatile("" ::: "memory");
    __builtin_amdgcn_s_barrier();
  }
  asm volatile("s_waitcnt vmcnt(0)" ::: "memory");
  __builtin_amdgcn_s_barrier();
  COMPUTE(1);

  // epilogue: store |acc|, LDS histogram (reuse staging LDS), flush
  __syncthreads();
  unsigned* shh = (unsigned*)&AsH[0][0];   // 16 KB of 32 KB
  for(int i = t; i < NQBIN; i += 512) shh[i] = 0;
  __syncthreads();

  float* rimg = res + (size_t)img * HW;
  #pragma unroll
  for(int i = 0; i < 4; i++)
    #pragma unroll
    for(int j = 0; j < 2; j++){
      f32x4 a = acc[i][j];
      int w  = w0 + wn + j*16 + fr;
      int hp = hp0 + wm + i*16 + fg*4;
      #pragma unroll
      for(int r = 0; r < 4; r++){
        float v = fabsf(a[r]);
        rimg[((size_t)(hp + r) << 9) + w] = v;
        atomicAdd(&shh[min((int)(v * 256.f), NQBIN - 1)], 1u);
      }
    }
  __syncthreads();

  unsigned* hg = qh + (size_t)img * NQBIN;
  for(int i = t; i < NQBIN; i += 512){
    unsigned c = shh[i];
    if(c) atomicAdd(&hg[i], c);
  }
}

// ---- percentiles (linear interp at 3% / 97%) -> (lo, 1/(hi-lo)) ----
__global__ void k_pct(const unsigned* __restrict__ qh, float2* __restrict__ prm){
  int img = blockIdx.x, t = threadIdx.x;
  const unsigned* h = qh + (size_t)img * NQBIN;
  __shared__ unsigned sh[NQBIN];
  for(int i = t; i < NQBIN; i += 256) sh[i] = h[i];
  __syncthreads();
  if(t == 0){
    const unsigned targ[4] = {7864u, 7865u, 254278u, 254279u};
    float v[4]; unsigned cum = 0; int b = 0;
    for(int q = 0; q < 4; q++){
      while(cum + sh[b] <= targ[q]){ cum += sh[b]; ++b; }
      v[q] = (float)b * (1.0f / 256.0f);
    }
    double plo = 0.03 * 262143.0;
    double phi = 0.97 * 262143.0;
    float lo = v[0] + (float)(plo - 7864.0)   * (v[1] - v[0]);
    float hi = v[2] + (float)(phi - 254278.0) * (v[3] - v[2]);
    prm[img] = make_float2(lo, 1.0f / (hi - lo));
  }
}

// ---- in-place normalize: out = (res - lo) * inv * mask ----
__global__ __launch_bounds__(256) void k_norm(float* __restrict__ out, const float* __restrict__ mask,
                                              const float2* __restrict__ prm){
  size_t i4 = (size_t)blockIdx.x * blockDim.x + threadIdx.x;
  const size_t total4 = (size_t)NIMG * HW / 4;
  const size_t step = (size_t)gridDim.x * blockDim.x;
  for(; i4 < total4; i4 += step){
    size_t i = i4 * 4;
    int bc = (int)(i >> 18);
    int bb = bc / 3;
    size_t mi = ((size_t)bb << 18) + (i & 0x3FFFFu);
    float4 r = *(float4*)(out + i);
    float4 m = *(const float4*)(mask + mi);
    float2 p = prm[bc];
    float4 o;
    o.x = (r.x - p.x) * p.y * m.x;
    o.y = (r.y - p.x) * p.y * m.y;
    o.z = (r.z - p.x) * p.y * m.z;
    o.w = (r.w - p.x) * p.y * m.w;
    *(float4*)(out + i) = o;
  }
}

extern "C" void kernel_launch(void* const* d_in, const int* in_sizes, int n_in,
                              void* d_out, int out_size, void* d_ws, size_t ws_size,
                              hipStream_t stream)
{
  const float* x       = (const float*)d_in[0];
  const float* mask    = (const float*)d_in[1];
  const float* fmap_in = (const float*)d_in[2];
  float* out = (float*)d_out;

  const size_t T1_BYTES = (size_t)NIMG * HW * 2;   // 48 MiB (bf16 t1T)
  char* ws = (char*)d_ws;
  unsigned short* t1h = (unsigned short*)ws;                    // lives rowpass..colpass
  // aliases with non-overlapping lifetimes:
  unsigned* h1 = (unsigned*)ws;                                 // dead before rowpass writes t1h
  unsigned* h2 = (unsigned*)(ws + (size_t)NIMG * 4096 * 4);
  unsigned* qh = (unsigned*)(ws + T1_BYTES);                    // own region (1.5 MB)
  char* tail = ws + T1_BYTES + (size_t)NIMG * NQBIN * 4;
  float*          Dir = (float*)tail;                           // 2048 B
  unsigned short* CmH = (unsigned short*)(tail + 2048);         // 512 KB
  char* tail2 = tail + 2048 + 524288;
  float*  med  = (float*)tail2;
  uint2*  sel1 = (uint2*)(tail2 + 512);
  float2* prm  = (float2*)(tail2 + 1536);

  k_dir<<<512, 256, 0, stream>>>(fmap_in, Dir);
  k_cmat<<<512, 256, 0, stream>>>(Dir, CmH);

  // 2-pass LDS radix select: median prefix to 24 bits (midpoint, err <= 8e-6)
  hipMemsetAsync(h1, 0, (size_t)NIMG * 4096 * 4 * 2, stream);
  k_p1<<<NIMG * 8, 256, 0, stream>>>(x, h1);
  k_scan1<<<NIMG, 256, 0, stream>>>(h1, sel1);
  k_p2<<<NIMG * 8, 256, 0, stream>>>(x, sel1, h2);
  k_scan_med<<<NIMG, 256, 0, stream>>>(h2, sel1, med);

  hipMemsetAsync(qh, 0, (size_t)NIMG * NQBIN * 4, stream);
  k_rowpass<<<1536, 512, 0, stream>>>(x, mask, med, CmH, t1h);
  k_colpass<<<1536, 512, 0, stream>>>(t1h, CmH, out, qh);

  k_pct<<<NIMG, 256, 0, stream>>>(qh, prm);
  k_norm<<<2048, 256, 0, stream>>>(out, mask, prm);
}

// Round 15
// 220.888 us; speedup vs baseline: 1.1853x; 1.1853x over previous
//
#include <hip/hip_runtime.h>
#include <math.h>

#define HW 262144     // 512*512
#define NIMG 96       // B*C
#define NQBIN 4096

typedef __attribute__((ext_vector_type(8))) short bf16x8;
typedef __attribute__((ext_vector_type(4))) float f32x4;

// ---- helpers ----
__device__ __forceinline__ unsigned fmap_u(float f){
  unsigned u = __float_as_uint(f);
  return (u & 0x80000000u) ? ~u : (u | 0x80000000u);
}
__device__ __forceinline__ float funmap_u(unsigned u){
  unsigned v = (u & 0x80000000u) ? (u & 0x7fffffffu) : ~u;
  return __uint_as_float(v);
}
__device__ __forceinline__ unsigned bf16rne(float f){
  unsigned u = __float_as_uint(f);
  return (u + 0x7fffu + ((u >> 16) & 1u)) >> 16;
}

// global -> LDS direct DMA, 16 B per lane. LDS dest = wave-uniform base + lane*16.
typedef __attribute__((address_space(3))) unsigned lds_u;
typedef const __attribute__((address_space(1))) unsigned glb_u;
__device__ __forceinline__ void gll16(const void* g, void* l){
  __builtin_amdgcn_global_load_lds((glb_u*)g, (lds_u*)l, 16, 0, 0);
}

// ---- Dir[n] = Re( ifft(filter_map row 0) )[n], computed in double ----
__global__ void k_dir(const float* __restrict__ fmap_in, float* __restrict__ Dir){
  int n = blockIdx.x;
  int t = threadIdx.x;
  double s = 0.0;
  for(int c = t; c < 512; c += 256){
    int a = (c * n) & 511;
    s += (double)fmap_in[c] * cos(6.283185307179586476925287 * (double)a / 512.0);
  }
  __shared__ double red[256];
  red[t] = s; __syncthreads();
  for(int off = 128; off; off >>= 1){
    if(t < off) red[t] += red[t + off];
    __syncthreads();
  }
  if(t == 0) Dir[n] = (float)(red[0] / 512.0);
}

// ---- Cm[a][b] = bf16( Dir[(a-b)&511] )  (512 KB, L2-resident) ----
__global__ void k_cmat(const float* __restrict__ Dir, unsigned short* __restrict__ CmH){
  int a = blockIdx.x;
  for(int b = threadIdx.x; b < 512; b += 256){
    float d = Dir[(a - b) & 511];
    CmH[(size_t)a * 512 + b] = (unsigned short)bf16rne(d);
  }
}

// ==== median via single 12-bit radix histogram + in-bin interpolation ====
// p1: dual sub-histogram (even/odd thread) to halve same-bin atomic serialization
__global__ __launch_bounds__(256) void k_p1(const float* __restrict__ x, unsigned* __restrict__ h){
  __shared__ unsigned sh[2][4112];   // bank-offset second copy
  const int img  = blockIdx.x >> 3;
  const int part = blockIdx.x & 7;
  const int par  = threadIdx.x & 1;
  const float4* p = (const float4*)(x + (size_t)img * HW + (size_t)part * 32768);
  for(int i = threadIdx.x; i < 4112; i += 256){ sh[0][i] = 0; sh[1][i] = 0; }
  __syncthreads();
  unsigned* mine = sh[par];
  for(int i = threadIdx.x; i < 8192; i += 256){
    float4 v = p[i];
    atomicAdd(&mine[fmap_u(v.x) >> 20], 1u);
    atomicAdd(&mine[fmap_u(v.y) >> 20], 1u);
    atomicAdd(&mine[fmap_u(v.z) >> 20], 1u);
    atomicAdd(&mine[fmap_u(v.w) >> 20], 1u);
  }
  __syncthreads();
  unsigned* hh = h + (size_t)img * 4096;
  for(int i = threadIdx.x; i < 4096; i += 256){
    unsigned c = sh[0][i] + sh[1][i];
    if(c) atomicAdd(&hh[i], c);
  }
}

// scan + interpolate: med = funmap( bin<<20 + frac*2^20 ) + 0.2
// 12-bit bin width ~2^-3 relative -> med error ~1e-4 abs for N(0,1) (negligible)
__global__ void k_med12(const unsigned* __restrict__ h, float* __restrict__ med){
  int img = blockIdx.x, t = threadIdx.x;
  const unsigned* hh = h + (size_t)img * 4096;
  __shared__ unsigned csum[256];
  unsigned s = 0;
  for(int j = 0; j < 16; j++) s += hh[t * 16 + j];
  csum[t] = s; __syncthreads();
  if(t == 0){
    unsigned k = 131071u, cum = 0; int chunk = 0;
    for(; chunk < 256; ++chunk){ if(cum + csum[chunk] > k) break; cum += csum[chunk]; }
    int b = chunk * 16;
    unsigned c;
    for(;; ++b){ c = hh[b]; if(cum + c > k) break; cum += c; }
    float frac = ((float)(k - cum) + 0.5f) / (float)c;
    unsigned m = ((unsigned)b << 20) + (unsigned)(frac * 1048576.0f);
    med[img] = funmap_u(m) + 0.2f;
  }
}

// ==== MFMA row pass: fused pad+convert A (reg-staged, depth-1) + DMA B ====
// t1T[img][n][h] = bf16( sum_k (mask?x:med)[r][k] * Cm[n][k] )
__global__ __launch_bounds__(512, 4) void k_rowpass(
    const float* __restrict__ x, const float* __restrict__ mask,
    const float* __restrict__ med,
    const unsigned short* __restrict__ CmH,
    unsigned short* __restrict__ t1h)
{
  __shared__ __align__(16) unsigned short As [2][8192];
  __shared__ __align__(16) unsigned short BsH[2][8192];

  // XCD swizzle: 4 sibling n-blocks (same x rows) on the same XCD
  const int b    = blockIdx.x;           // 0..1535
  const int xcd  = b & 7;
  const int i8   = b >> 3;               // 0..191
  const int rblk = xcd * 48 + (i8 >> 2); // 0..383
  const int nblk = i8 & 3;
  const int r0 = rblk * 128;
  const int n0 = nblk * 128;
  const int bc = r0 >> 9;
  const int bb = bc / 3;
  const float mv = med[bc];

  const int t    = threadIdx.x;
  const int lane = t & 63;
  const int wv   = t >> 6;               // 0..7
  const int wm   = (wv >> 2) * 64;
  const int wn   = (wv & 3) * 32;
  const int fr   = lane & 15;
  const int fg   = lane >> 4;
  const int sw   = lane & 7;

  // A reg-staging: thread -> row t>>2, 16 cols at (t&3)*16
  const int srow = t >> 2;
  const int sc   = (t & 3) << 4;
  const float* xr = x    + ((size_t)(r0 + srow) << 9) + sc;
  const float* mr = mask + (size_t)bb * HW + ((size_t)((r0 + srow) & 511) << 9) + sc;

  // B DMA mapping
  const int drow = lane >> 3;
  const int dblk = (lane & 7) ^ drow;
  const unsigned short* bhsrc = CmH + ((size_t)(n0 + wv*8 + drow) << 9) + dblk * 8;
  const int dbase = wv * 8 * 64;

  f32x4 acc[4][2];
  #pragma unroll
  for(int i = 0; i < 4; i++)
    #pragma unroll
    for(int j = 0; j < 2; j++) acc[i][j] = (f32x4){0.f, 0.f, 0.f, 0.f};

  float4 px[4], pm[4];

  auto ALOAD = [&](int k0){
    #pragma unroll
    for(int q = 0; q < 4; q++){
      px[q] = *(const float4*)(xr + k0 + q * 4);
      pm[q] = *(const float4*)(mr + k0 + q * 4);
    }
  };
  auto BDMA = [&](int buf, int k0){
    #pragma unroll
    for(int q = 0; q < 2; q++){
      const size_t so = ((size_t)(q * 64) << 9) + k0;
      const int    dq = dbase + q * 4096;
      gll16(bhsrc + so, &BsH[buf][dq]);
    }
  };
  auto ACONV = [&](int buf){
    unsigned hp[8];
    #pragma unroll
    for(int q = 0; q < 4; q++){
      unsigned h0 = bf16rne((pm[q].x != 0.f) ? px[q].x : mv);
      unsigned h1 = bf16rne((pm[q].y != 0.f) ? px[q].y : mv);
      unsigned h2 = bf16rne((pm[q].z != 0.f) ? px[q].z : mv);
      unsigned h3 = bf16rne((pm[q].w != 0.f) ? px[q].w : mv);
      hp[q*2]   = (h1 << 16) | h0;
      hp[q*2+1] = (h3 << 16) | h2;
    }
    const int b0 = (t & 3) * 2;
    *(uint4*)&As[buf][srow * 64 + (( b0      ^ (srow & 7)) << 3)] = make_uint4(hp[0], hp[1], hp[2], hp[3]);
    *(uint4*)&As[buf][srow * 64 + (((b0 | 1) ^ (srow & 7)) << 3)] = make_uint4(hp[4], hp[5], hp[6], hp[7]);
  };
  auto COMPUTE = [&](int buf){
    bf16x8 af[4][2], bh[2][2];
    #pragma unroll
    for(int i = 0; i < 4; i++)
      #pragma unroll
      for(int kq = 0; kq < 2; kq++){
        int row = wm + i*16 + fr;
        af[i][kq] = *(const bf16x8*)&As[buf][row*64 + (((kq*4 + fg) ^ sw) << 3)];
      }
    #pragma unroll
    for(int j = 0; j < 2; j++)
      #pragma unroll
      for(int kq = 0; kq < 2; kq++){
        int row = wn + j*16 + fr;
        bh[j][kq] = *(const bf16x8*)&BsH[buf][row*64 + (((kq*4 + fg) ^ sw) << 3)];
      }
    __builtin_amdgcn_s_setprio(1);
    #pragma unroll
    for(int i = 0; i < 4; i++)
      #pragma unroll
      for(int j = 0; j < 2; j++){
        acc[i][j] = __builtin_amdgcn_mfma_f32_16x16x32_bf16(af[i][0], bh[j][0], acc[i][j], 0, 0, 0);
        acc[i][j] = __builtin_amdgcn_mfma_f32_16x16x32_bf16(af[i][1], bh[j][1], acc[i][j], 0, 0, 0);
      }
    __builtin_amdgcn_s_setprio(0);
  };

  // prologue: tile 0 (8 A-loads then 2 B-DMA outstanding)
  ALOAD(0); BDMA(0, 0);
  asm volatile("s_waitcnt vmcnt(2)" ::: "memory");   // A-loads done
  ACONV(0);
  asm volatile("s_waitcnt vmcnt(0) lgkmcnt(0)" ::: "memory");
  __builtin_amdgcn_sched_barrier(0);
  __builtin_amdgcn_s_barrier();

  #pragma unroll
  for(int it = 0; it < 7; ++it){
    ALOAD((it + 1) * 64);                 // next tile A -> regs (flies under compute)
    BDMA((it + 1) & 1, (it + 1) * 64);    // next tile B -> LDS DMA
    COMPUTE(it & 1);
    asm volatile("s_waitcnt vmcnt(2)" ::: "memory");   // A-loads landed, B-DMA may fly
    ACONV((it + 1) & 1);
    asm volatile("s_waitcnt vmcnt(0) lgkmcnt(0)" ::: "memory");
    __builtin_amdgcn_sched_barrier(0);
    __builtin_amdgcn_s_barrier();
  }
  COMPUTE(1);

  // epilogue: t1 transposed single bf16
  const int img = r0 >> 9;
  const int hb  = r0 & 511;
  #pragma unroll
  for(int i = 0; i < 4; i++)
    #pragma unroll
    for(int j = 0; j < 2; j++){
      f32x4 a = acc[i][j];
      unsigned b0 = bf16rne(a[0]), b1 = bf16rne(a[1]), b2 = bf16rne(a[2]), b3 = bf16rne(a[3]);
      int n = n0 + wn + j*16 + fr;
      int h = hb + wm + i*16 + fg*4;
      *(uint2*)&t1h[(size_t)img * HW + ((size_t)n << 9) + h] =
          make_uint2((b1<<16)|b0, (b3<<16)|b2);
    }
}

// ==== MFMA col pass: single-bf16 A (CmH), 64 KB LDS -> 2 blocks/CU; fused q-hist ====
__global__ __launch_bounds__(512, 4) void k_colpass(
    const unsigned short* __restrict__ t1h,
    const unsigned short* __restrict__ CmH,
    float* __restrict__ res, unsigned* __restrict__ qh)
{
  __shared__ __align__(16) unsigned short AsH[2][8192];
  __shared__ __align__(16) unsigned short Bs [2][8192];

  // XCD swizzle: all 16 blocks of one image on the same XCD (t1 image L2-resident)
  const int b    = blockIdx.x;           // 0..1535
  const int xcd  = b & 7;
  const int i8   = b >> 3;               // 0..191
  const int img  = xcd * 12 + (i8 >> 4);
  const int r16  = i8 & 15;
  const int hp0  = (r16 >> 2) * 128;
  const int w0   = (r16 & 3) * 128;

  const int t    = threadIdx.x;
  const int lane = t & 63;
  const int wv   = t >> 6;
  const int wm   = (wv >> 2) * 64;
  const int wn   = (wv & 3) * 32;
  const int fr   = lane & 15;
  const int fg   = lane >> 4;
  const int sw   = lane & 7;

  const int drow = lane >> 3;
  const int dblk = (lane & 7) ^ drow;
  const unsigned short* ahsrc = CmH + ((size_t)(hp0 + wv*8 + drow) << 9) + dblk * 8;
  const unsigned short* bsrc  = t1h + (size_t)img * HW + ((size_t)(w0 + wv*8 + drow) << 9) + dblk * 8;
  const int dbase = wv * 8 * 64;

  f32x4 acc[4][2];
  #pragma unroll
  for(int i = 0; i < 4; i++)
    #pragma unroll
    for(int j = 0; j < 2; j++) acc[i][j] = (f32x4){0.f, 0.f, 0.f, 0.f};

  auto STAGE = [&](int buf, int k0){
    #pragma unroll
    for(int q = 0; q < 2; q++){
      const size_t so = ((size_t)(q * 64) << 9) + k0;
      const int    dq = dbase + q * 4096;
      gll16(ahsrc + so, &AsH[buf][dq]);
      gll16(bsrc  + so, &Bs [buf][dq]);
    }
  };
  auto COMPUTE = [&](int buf){
    bf16x8 ah[4][2], bv[2][2];
    #pragma unroll
    for(int i = 0; i < 4; i++)
      #pragma unroll
      for(int kq = 0; kq < 2; kq++){
        int row = wm + i*16 + fr;
        ah[i][kq] = *(const bf16x8*)&AsH[buf][row*64 + (((kq*4 + fg) ^ sw) << 3)];
      }
    #pragma unroll
    for(int j = 0; j < 2; j++)
      #pragma unroll
      for(int kq = 0; kq < 2; kq++){
        int row = wn + j*16 + fr;
        bv[j][kq] = *(const bf16x8*)&Bs[buf][row*64 + (((kq*4 + fg) ^ sw) << 3)];
      }
    __builtin_amdgcn_s_setprio(1);
    #pragma unroll
    for(int i = 0; i < 4; i++)
      #pragma unroll
      for(int j = 0; j < 2; j++){
        acc[i][j] = __builtin_amdgcn_mfma_f32_16x16x32_bf16(ah[i][0], bv[j][0], acc[i][j], 0, 0, 0);
        acc[i][j] = __builtin_amdgcn_mfma_f32_16x16x32_bf16(ah[i][1], bv[j][1], acc[i][j], 0, 0, 0);
      }
    __builtin_amdgcn_s_setprio(0);
  };

  STAGE(0, 0);
  asm volatile("s_waitcnt vmcnt(0)" ::: "memory");
  __builtin_amdgcn_s_barrier();
  #pragma unroll
  for(int it = 0; it < 7; ++it){
    STAGE((it + 1) & 1, (it + 1) * 64);
    asm volatile("s_waitcnt vmcnt(4)" ::: "memory");   // drain tile it, keep it+1 in flight
    __builtin_amdgcn_s_barrier();
    COMPUTE(it & 1);
    asm volatile("" ::: "memory");
    __builtin_amdgcn_s_barrier();
  }
  asm volatile("s_waitcnt vmcnt(0)" ::: "memory");
  __builtin_amdgcn_s_barrier();
  COMPUTE(1);

  // epilogue: store |acc|, LDS histogram (reuse staging LDS), flush
  __syncthreads();
  unsigned* shh = (unsigned*)&AsH[0][0];   // 16 KB of 32 KB
  for(int i = t; i < NQBIN; i += 512) shh[i] = 0;
  __syncthreads();

  float* rimg = res + (size_t)img * HW;
  #pragma unroll
  for(int i = 0; i < 4; i++)
    #pragma unroll
    for(int j = 0; j < 2; j++){
      f32x4 a = acc[i][j];
      int w  = w0 + wn + j*16 + fr;
      int hp = hp0 + wm + i*16 + fg*4;
      #pragma unroll
      for(int r = 0; r < 4; r++){
        float v = fabsf(a[r]);
        rimg[((size_t)(hp + r) << 9) + w] = v;
        atomicAdd(&shh[min((int)(v * 256.f), NQBIN - 1)], 1u);
      }
    }
  __syncthreads();

  unsigned* hg = qh + (size_t)img * NQBIN;
  for(int i = t; i < NQBIN; i += 512){
    unsigned c = shh[i];
    if(c) atomicAdd(&hg[i], c);
  }
}

// ---- percentiles (linear interp at 3% / 97%) -> (lo, 1/(hi-lo)) ----
__global__ void k_pct(const unsigned* __restrict__ qh, float2* __restrict__ prm){
  int img = blockIdx.x, t = threadIdx.x;
  const unsigned* h = qh + (size_t)img * NQBIN;
  __shared__ unsigned sh[NQBIN];
  for(int i = t; i < NQBIN; i += 256) sh[i] = h[i];
  __syncthreads();
  if(t == 0){
    const unsigned targ[4] = {7864u, 7865u, 254278u, 254279u};
    float v[4]; unsigned cum = 0; int b = 0;
    for(int q = 0; q < 4; q++){
      while(cum + sh[b] <= targ[q]){ cum += sh[b]; ++b; }
      v[q] = (float)b * (1.0f / 256.0f);
    }
    double plo = 0.03 * 262143.0;
    double phi = 0.97 * 262143.0;
    float lo = v[0] + (float)(plo - 7864.0)   * (v[1] - v[0]);
    float hi = v[2] + (float)(phi - 254278.0) * (v[3] - v[2]);
    prm[img] = make_float2(lo, 1.0f / (hi - lo));
  }
}

// ---- in-place normalize: out = (res - lo) * inv * mask ----
__global__ __launch_bounds__(256) void k_norm(float* __restrict__ out, const float* __restrict__ mask,
                                              const float2* __restrict__ prm){
  size_t i4 = (size_t)blockIdx.x * blockDim.x + threadIdx.x;
  const size_t total4 = (size_t)NIMG * HW / 4;
  const size_t step = (size_t)gridDim.x * blockDim.x;
  for(; i4 < total4; i4 += step){
    size_t i = i4 * 4;
    int bc = (int)(i >> 18);
    int bb = bc / 3;
    size_t mi = ((size_t)bb << 18) + (i & 0x3FFFFu);
    float4 r = *(float4*)(out + i);
    float4 m = *(const float4*)(mask + mi);
    float2 p = prm[bc];
    float4 o;
    o.x = (r.x - p.x) * p.y * m.x;
    o.y = (r.y - p.x) * p.y * m.y;
    o.z = (r.z - p.x) * p.y * m.z;
    o.w = (r.w - p.x) * p.y * m.w;
    *(float4*)(out + i) = o;
  }
}

extern "C" void kernel_launch(void* const* d_in, const int* in_sizes, int n_in,
                              void* d_out, int out_size, void* d_ws, size_t ws_size,
                              hipStream_t stream)
{
  const float* x       = (const float*)d_in[0];
  const float* mask    = (const float*)d_in[1];
  const float* fmap_in = (const float*)d_in[2];
  float* out = (float*)d_out;

  const size_t T1_BYTES = (size_t)NIMG * HW * 2;   // 48 MiB (bf16 t1T)
  char* ws = (char*)d_ws;
  unsigned short* t1h = (unsigned short*)ws;                    // lives rowpass..colpass
  // aliases with non-overlapping lifetimes:
  unsigned* h1 = (unsigned*)ws;                                 // dead before rowpass writes t1h
  unsigned* qh = (unsigned*)(ws + T1_BYTES);                    // own region (1.5 MB)
  char* tail = ws + T1_BYTES + (size_t)NIMG * NQBIN * 4;
  float*          Dir = (float*)tail;                           // 2048 B
  unsigned short* CmH = (unsigned short*)(tail + 2048);         // 512 KB
  char* tail2 = tail + 2048 + 524288;
  float*  med  = (float*)tail2;                                 // 512 B slot
  float2* prm  = (float2*)(tail2 + 512);                        // 768 B

  k_dir<<<512, 256, 0, stream>>>(fmap_in, Dir);
  k_cmat<<<512, 256, 0, stream>>>(Dir, CmH);

  // single-pass 12-bit radix histogram + interpolated median (err ~1e-4)
  hipMemsetAsync(h1, 0, (size_t)NIMG * 4096 * 4, stream);
  k_p1<<<NIMG * 8, 256, 0, stream>>>(x, h1);
  k_med12<<<NIMG, 256, 0, stream>>>(h1, med);

  hipMemsetAsync(qh, 0, (size_t)NIMG * NQBIN * 4, stream);
  k_rowpass<<<1536, 512, 0, stream>>>(x, mask, med, CmH, t1h);
  k_colpass<<<1536, 512, 0, stream>>>(t1h, CmH, out, qh);

  k_pct<<<NIMG, 256, 0, stream>>>(qh, prm);
  k_norm<<<2048, 256, 0, stream>>>(out, mask, prm);
}

// Round 16
// 216.386 us; speedup vs baseline: 1.2099x; 1.0208x over previous
//
#include <hip/hip_runtime.h>
#include <math.h>

#define HW 262144     // 512*512
#define NIMG 96       // B*C
#define NQBIN 4096

typedef __attribute__((ext_vector_type(8))) short bf16x8;
typedef __attribute__((ext_vector_type(4))) float f32x4;

// ---- helpers ----
__device__ __forceinline__ unsigned fmap_u(float f){
  unsigned u = __float_as_uint(f);
  return (u & 0x80000000u) ? ~u : (u | 0x80000000u);
}
__device__ __forceinline__ float funmap_u(unsigned u){
  unsigned v = (u & 0x80000000u) ? (u & 0x7fffffffu) : ~u;
  return __uint_as_float(v);
}
__device__ __forceinline__ unsigned bf16rne(float f){
  unsigned u = __float_as_uint(f);
  return (u + 0x7fffu + ((u >> 16) & 1u)) >> 16;
}

// global -> LDS direct DMA, 16 B per lane. LDS dest = wave-uniform base + lane*16.
typedef __attribute__((address_space(3))) unsigned lds_u;
typedef const __attribute__((address_space(1))) unsigned glb_u;
__device__ __forceinline__ void gll16(const void* g, void* l){
  __builtin_amdgcn_global_load_lds((glb_u*)g, (lds_u*)l, 16, 0, 0);
}

// ---- Dir[n] = Re( ifft(filter_map row 0) )[n], computed in double ----
__global__ void k_dir(const float* __restrict__ fmap_in, float* __restrict__ Dir){
  int n = blockIdx.x;
  int t = threadIdx.x;
  double s = 0.0;
  for(int c = t; c < 512; c += 256){
    int a = (c * n) & 511;
    s += (double)fmap_in[c] * cos(6.283185307179586476925287 * (double)a / 512.0);
  }
  __shared__ double red[256];
  red[t] = s; __syncthreads();
  for(int off = 128; off; off >>= 1){
    if(t < off) red[t] += red[t + off];
    __syncthreads();
  }
  if(t == 0) Dir[n] = (float)(red[0] / 512.0);
}

// ---- Cm[a][b] = bf16( Dir[(a-b)&511] )  (512 KB, L2-resident) ----
__global__ void k_cmat(const float* __restrict__ Dir, unsigned short* __restrict__ CmH){
  int a = blockIdx.x;
  for(int b = threadIdx.x; b < 512; b += 256){
    float d = Dir[(a - b) & 511];
    CmH[(size_t)a * 512 + b] = (unsigned short)bf16rne(d);
  }
}

// ==== median via single 12-bit radix histogram + in-bin interpolation ====
__global__ __launch_bounds__(256) void k_p1(const float* __restrict__ x, unsigned* __restrict__ h){
  __shared__ unsigned sh[2][4112];   // dual sub-histogram, bank-offset copy
  const int img  = blockIdx.x >> 3;
  const int part = blockIdx.x & 7;
  const int par  = threadIdx.x & 1;
  const float4* p = (const float4*)(x + (size_t)img * HW + (size_t)part * 32768);
  for(int i = threadIdx.x; i < 4112; i += 256){ sh[0][i] = 0; sh[1][i] = 0; }
  __syncthreads();
  unsigned* mine = sh[par];
  for(int i = threadIdx.x; i < 8192; i += 256){
    float4 v = p[i];
    atomicAdd(&mine[fmap_u(v.x) >> 20], 1u);
    atomicAdd(&mine[fmap_u(v.y) >> 20], 1u);
    atomicAdd(&mine[fmap_u(v.z) >> 20], 1u);
    atomicAdd(&mine[fmap_u(v.w) >> 20], 1u);
  }
  __syncthreads();
  unsigned* hh = h + (size_t)img * 4096;
  for(int i = threadIdx.x; i < 4096; i += 256){
    unsigned c = sh[0][i] + sh[1][i];
    if(c) atomicAdd(&hh[i], c);
  }
}

// scan + interpolate: med error ~1e-4 abs for N(0,1) (negligible vs bin granularity)
__global__ void k_med12(const unsigned* __restrict__ h, float* __restrict__ med){
  int img = blockIdx.x, t = threadIdx.x;
  const unsigned* hh = h + (size_t)img * 4096;
  __shared__ unsigned csum[256];
  unsigned s = 0;
  for(int j = 0; j < 16; j++) s += hh[t * 16 + j];
  csum[t] = s; __syncthreads();
  if(t == 0){
    unsigned k = 131071u, cum = 0; int chunk = 0;
    for(; chunk < 256; ++chunk){ if(cum + csum[chunk] > k) break; cum += csum[chunk]; }
    int b = chunk * 16;
    unsigned c;
    for(;; ++b){ c = hh[b]; if(cum + c > k) break; cum += c; }
    float frac = ((float)(k - cum) + 0.5f) / (float)c;
    unsigned m = ((unsigned)b << 20) + (unsigned)(frac * 1048576.0f);
    med[img] = funmap_u(m) + 0.2f;
  }
}

// ==== MFMA row pass: fused pad+convert A (reg-staged, depth-1) + DMA B ====
__global__ __launch_bounds__(512, 4) void k_rowpass(
    const float* __restrict__ x, const float* __restrict__ mask,
    const float* __restrict__ med,
    const unsigned short* __restrict__ CmH,
    unsigned short* __restrict__ t1h)
{
  __shared__ __align__(16) unsigned short As [2][8192];
  __shared__ __align__(16) unsigned short BsH[2][8192];

  const int b    = blockIdx.x;           // 0..1535
  const int xcd  = b & 7;
  const int i8   = b >> 3;
  const int rblk = xcd * 48 + (i8 >> 2);
  const int nblk = i8 & 3;
  const int r0 = rblk * 128;
  const int n0 = nblk * 128;
  const int bc = r0 >> 9;
  const int bb = bc / 3;
  const float mv = med[bc];

  const int t    = threadIdx.x;
  const int lane = t & 63;
  const int wv   = t >> 6;
  const int wm   = (wv >> 2) * 64;
  const int wn   = (wv & 3) * 32;
  const int fr   = lane & 15;
  const int fg   = lane >> 4;
  const int sw   = lane & 7;

  const int srow = t >> 2;
  const int sc   = (t & 3) << 4;
  const float* xr = x    + ((size_t)(r0 + srow) << 9) + sc;
  const float* mr = mask + (size_t)bb * HW + ((size_t)((r0 + srow) & 511) << 9) + sc;

  const int drow = lane >> 3;
  const int dblk = (lane & 7) ^ drow;
  const unsigned short* bhsrc = CmH + ((size_t)(n0 + wv*8 + drow) << 9) + dblk * 8;
  const int dbase = wv * 8 * 64;

  f32x4 acc[4][2];
  #pragma unroll
  for(int i = 0; i < 4; i++)
    #pragma unroll
    for(int j = 0; j < 2; j++) acc[i][j] = (f32x4){0.f, 0.f, 0.f, 0.f};

  float4 px[4], pm[4];

  auto ALOAD = [&](int k0){
    #pragma unroll
    for(int q = 0; q < 4; q++){
      px[q] = *(const float4*)(xr + k0 + q * 4);
      pm[q] = *(const float4*)(mr + k0 + q * 4);
    }
  };
  auto BDMA = [&](int buf, int k0){
    #pragma unroll
    for(int q = 0; q < 2; q++){
      const size_t so = ((size_t)(q * 64) << 9) + k0;
      const int    dq = dbase + q * 4096;
      gll16(bhsrc + so, &BsH[buf][dq]);
    }
  };
  auto ACONV = [&](int buf){
    unsigned hp[8];
    #pragma unroll
    for(int q = 0; q < 4; q++){
      unsigned h0 = bf16rne((pm[q].x != 0.f) ? px[q].x : mv);
      unsigned h1 = bf16rne((pm[q].y != 0.f) ? px[q].y : mv);
      unsigned h2 = bf16rne((pm[q].z != 0.f) ? px[q].z : mv);
      unsigned h3 = bf16rne((pm[q].w != 0.f) ? px[q].w : mv);
      hp[q*2]   = (h1 << 16) | h0;
      hp[q*2+1] = (h3 << 16) | h2;
    }
    const int b0 = (t & 3) * 2;
    *(uint4*)&As[buf][srow * 64 + (( b0      ^ (srow & 7)) << 3)] = make_uint4(hp[0], hp[1], hp[2], hp[3]);
    *(uint4*)&As[buf][srow * 64 + (((b0 | 1) ^ (srow & 7)) << 3)] = make_uint4(hp[4], hp[5], hp[6], hp[7]);
  };
  auto COMPUTE = [&](int buf){
    bf16x8 af[4][2], bh[2][2];
    #pragma unroll
    for(int i = 0; i < 4; i++)
      #pragma unroll
      for(int kq = 0; kq < 2; kq++){
        int row = wm + i*16 + fr;
        af[i][kq] = *(const bf16x8*)&As[buf][row*64 + (((kq*4 + fg) ^ sw) << 3)];
      }
    #pragma unroll
    for(int j = 0; j < 2; j++)
      #pragma unroll
      for(int kq = 0; kq < 2; kq++){
        int row = wn + j*16 + fr;
        bh[j][kq] = *(const bf16x8*)&BsH[buf][row*64 + (((kq*4 + fg) ^ sw) << 3)];
      }
    __builtin_amdgcn_s_setprio(1);
    #pragma unroll
    for(int i = 0; i < 4; i++)
      #pragma unroll
      for(int j = 0; j < 2; j++){
        acc[i][j] = __builtin_amdgcn_mfma_f32_16x16x32_bf16(af[i][0], bh[j][0], acc[i][j], 0, 0, 0);
        acc[i][j] = __builtin_amdgcn_mfma_f32_16x16x32_bf16(af[i][1], bh[j][1], acc[i][j], 0, 0, 0);
      }
    __builtin_amdgcn_s_setprio(0);
  };

  ALOAD(0); BDMA(0, 0);
  asm volatile("s_waitcnt vmcnt(2)" ::: "memory");
  ACONV(0);
  asm volatile("s_waitcnt vmcnt(0) lgkmcnt(0)" ::: "memory");
  __builtin_amdgcn_sched_barrier(0);
  __builtin_amdgcn_s_barrier();

  #pragma unroll
  for(int it = 0; it < 7; ++it){
    ALOAD((it + 1) * 64);
    BDMA((it + 1) & 1, (it + 1) * 64);
    COMPUTE(it & 1);
    asm volatile("s_waitcnt vmcnt(2)" ::: "memory");
    ACONV((it + 1) & 1);
    asm volatile("s_waitcnt vmcnt(0) lgkmcnt(0)" ::: "memory");
    __builtin_amdgcn_sched_barrier(0);
    __builtin_amdgcn_s_barrier();
  }
  COMPUTE(1);

  const int img = r0 >> 9;
  const int hb  = r0 & 511;
  #pragma unroll
  for(int i = 0; i < 4; i++)
    #pragma unroll
    for(int j = 0; j < 2; j++){
      f32x4 a = acc[i][j];
      unsigned b0 = bf16rne(a[0]), b1 = bf16rne(a[1]), b2 = bf16rne(a[2]), b3 = bf16rne(a[3]);
      int n = n0 + wn + j*16 + fr;
      int h = hb + wm + i*16 + fg*4;
      *(uint2*)&t1h[(size_t)img * HW + ((size_t)n << 9) + h] =
          make_uint2((b1<<16)|b0, (b3<<16)|b2);
    }
}

// ==== MFMA col pass: res stored as bf16 (halves WRITE + norm's re-read); fused q-hist ====
__global__ __launch_bounds__(512, 4) void k_colpass(
    const unsigned short* __restrict__ t1h,
    const unsigned short* __restrict__ CmH,
    unsigned short* __restrict__ resh, unsigned* __restrict__ qh)
{
  __shared__ __align__(16) unsigned short AsH[2][8192];
  __shared__ __align__(16) unsigned short Bs [2][8192];

  const int b    = blockIdx.x;           // 0..1535
  const int xcd  = b & 7;
  const int i8   = b >> 3;
  const int img  = xcd * 12 + (i8 >> 4);
  const int r16  = i8 & 15;
  const int hp0  = (r16 >> 2) * 128;
  const int w0   = (r16 & 3) * 128;

  const int t    = threadIdx.x;
  const int lane = t & 63;
  const int wv   = t >> 6;
  const int wm   = (wv >> 2) * 64;
  const int wn   = (wv & 3) * 32;
  const int fr   = lane & 15;
  const int fg   = lane >> 4;
  const int sw   = lane & 7;

  const int drow = lane >> 3;
  const int dblk = (lane & 7) ^ drow;
  const unsigned short* ahsrc = CmH + ((size_t)(hp0 + wv*8 + drow) << 9) + dblk * 8;
  const unsigned short* bsrc  = t1h + (size_t)img * HW + ((size_t)(w0 + wv*8 + drow) << 9) + dblk * 8;
  const int dbase = wv * 8 * 64;

  f32x4 acc[4][2];
  #pragma unroll
  for(int i = 0; i < 4; i++)
    #pragma unroll
    for(int j = 0; j < 2; j++) acc[i][j] = (f32x4){0.f, 0.f, 0.f, 0.f};

  auto STAGE = [&](int buf, int k0){
    #pragma unroll
    for(int q = 0; q < 2; q++){
      const size_t so = ((size_t)(q * 64) << 9) + k0;
      const int    dq = dbase + q * 4096;
      gll16(ahsrc + so, &AsH[buf][dq]);
      gll16(bsrc  + so, &Bs [buf][dq]);
    }
  };
  auto COMPUTE = [&](int buf){
    bf16x8 ah[4][2], bv[2][2];
    #pragma unroll
    for(int i = 0; i < 4; i++)
      #pragma unroll
      for(int kq = 0; kq < 2; kq++){
        int row = wm + i*16 + fr;
        ah[i][kq] = *(const bf16x8*)&AsH[buf][row*64 + (((kq*4 + fg) ^ sw) << 3)];
      }
    #pragma unroll
    for(int j = 0; j < 2; j++)
      #pragma unroll
      for(int kq = 0; kq < 2; kq++){
        int row = wn + j*16 + fr;
        bv[j][kq] = *(const bf16x8*)&Bs[buf][row*64 + (((kq*4 + fg) ^ sw) << 3)];
      }
    __builtin_amdgcn_s_setprio(1);
    #pragma unroll
    for(int i = 0; i < 4; i++)
      #pragma unroll
      for(int j = 0; j < 2; j++){
        acc[i][j] = __builtin_amdgcn_mfma_f32_16x16x32_bf16(ah[i][0], bv[j][0], acc[i][j], 0, 0, 0);
        acc[i][j] = __builtin_amdgcn_mfma_f32_16x16x32_bf16(ah[i][1], bv[j][1], acc[i][j], 0, 0, 0);
      }
    __builtin_amdgcn_s_setprio(0);
  };

  STAGE(0, 0);
  asm volatile("s_waitcnt vmcnt(0)" ::: "memory");
  __builtin_amdgcn_s_barrier();
  #pragma unroll
  for(int it = 0; it < 7; ++it){
    STAGE((it + 1) & 1, (it + 1) * 64);
    asm volatile("s_waitcnt vmcnt(4)" ::: "memory");
    __builtin_amdgcn_s_barrier();
    COMPUTE(it & 1);
    asm volatile("" ::: "memory");
    __builtin_amdgcn_s_barrier();
  }
  asm volatile("s_waitcnt vmcnt(0)" ::: "memory");
  __builtin_amdgcn_s_barrier();
  COMPUTE(1);

  // epilogue: store bf16 |acc| + LDS histogram (fp32 values), flush
  __syncthreads();
  unsigned* shh = (unsigned*)&AsH[0][0];
  for(int i = t; i < NQBIN; i += 512) shh[i] = 0;
  __syncthreads();

  unsigned short* rimg = resh + (size_t)img * HW;
  #pragma unroll
  for(int i = 0; i < 4; i++)
    #pragma unroll
    for(int j = 0; j < 2; j++){
      f32x4 a = acc[i][j];
      int w  = w0 + wn + j*16 + fr;
      int hp = hp0 + wm + i*16 + fg*4;
      #pragma unroll
      for(int r = 0; r < 4; r++){
        float v = fabsf(a[r]);
        rimg[((size_t)(hp + r) << 9) + w] = (unsigned short)bf16rne(v);
        atomicAdd(&shh[min((int)(v * 256.f), NQBIN - 1)], 1u);
      }
    }
  __syncthreads();

  unsigned* hg = qh + (size_t)img * NQBIN;
  for(int i = t; i < NQBIN; i += 512){
    unsigned c = shh[i];
    if(c) atomicAdd(&hg[i], c);
  }
}

// ---- percentiles (linear interp at 3% / 97%) -> (lo, 1/(hi-lo)) ----
__global__ void k_pct(const unsigned* __restrict__ qh, float2* __restrict__ prm){
  int img = blockIdx.x, t = threadIdx.x;
  const unsigned* h = qh + (size_t)img * NQBIN;
  __shared__ unsigned sh[NQBIN];
  for(int i = t; i < NQBIN; i += 256) sh[i] = h[i];
  __syncthreads();
  if(t == 0){
    const unsigned targ[4] = {7864u, 7865u, 254278u, 254279u};
    float v[4]; unsigned cum = 0; int b = 0;
    for(int q = 0; q < 4; q++){
      while(cum + sh[b] <= targ[q]){ cum += sh[b]; ++b; }
      v[q] = (float)b * (1.0f / 256.0f);
    }
    double plo = 0.03 * 262143.0;
    double phi = 0.97 * 262143.0;
    float lo = v[0] + (float)(plo - 7864.0)   * (v[1] - v[0]);
    float hi = v[2] + (float)(phi - 254278.0) * (v[3] - v[2]);
    prm[img] = make_float2(lo, 1.0f / (hi - lo));
  }
}

// ---- normalize: out = (bf16res - lo) * inv * mask  (bf16 in, fp32 out) ----
__global__ __launch_bounds__(256) void k_norm(const unsigned short* __restrict__ resh,
                                              const float* __restrict__ mask,
                                              const float2* __restrict__ prm,
                                              float* __restrict__ out){
  size_t i8 = (size_t)blockIdx.x * blockDim.x + threadIdx.x;
  const size_t total8 = (size_t)NIMG * HW / 8;
  const size_t step = (size_t)gridDim.x * blockDim.x;
  for(; i8 < total8; i8 += step){
    size_t i = i8 * 8;
    int bc = (int)(i >> 18);
    int bb = bc / 3;
    size_t mi = ((size_t)bb << 18) + (i & 0x3FFFFu);
    uint4 rv = *(const uint4*)(resh + i);
    float4 m0 = *(const float4*)(mask + mi);
    float4 m1 = *(const float4*)(mask + mi + 4);
    float2 p = prm[bc];
    float4 o0, o1;
    o0.x = (__uint_as_float((rv.x & 0xFFFFu) << 16) - p.x) * p.y * m0.x;
    o0.y = (__uint_as_float((rv.x & 0xFFFF0000u))   - p.x) * p.y * m0.y;
    o0.z = (__uint_as_float((rv.y & 0xFFFFu) << 16) - p.x) * p.y * m0.z;
    o0.w = (__uint_as_float((rv.y & 0xFFFF0000u))   - p.x) * p.y * m0.w;
    o1.x = (__uint_as_float((rv.z & 0xFFFFu) << 16) - p.x) * p.y * m1.x;
    o1.y = (__uint_as_float((rv.z & 0xFFFF0000u))   - p.x) * p.y * m1.y;
    o1.z = (__uint_as_float((rv.w & 0xFFFFu) << 16) - p.x) * p.y * m1.z;
    o1.w = (__uint_as_float((rv.w & 0xFFFF0000u))   - p.x) * p.y * m1.w;
    *(float4*)(out + i)     = o0;
    *(float4*)(out + i + 4) = o1;
  }
}

extern "C" void kernel_launch(void* const* d_in, const int* in_sizes, int n_in,
                              void* d_out, int out_size, void* d_ws, size_t ws_size,
                              hipStream_t stream)
{
  const float* x       = (const float*)d_in[0];
  const float* mask    = (const float*)d_in[1];
  const float* fmap_in = (const float*)d_in[2];
  float* out = (float*)d_out;

  const size_t T1_BYTES = (size_t)NIMG * HW * 2;   // 48 MiB each for t1h and resh
  const size_t QH_BYTES = (size_t)NIMG * NQBIN * 4;
  char* ws = (char*)d_ws;
  unsigned short* t1h  = (unsigned short*)ws;                       // rowpass..colpass
  unsigned*       qh   = (unsigned*)(ws + T1_BYTES);                // 1.5 MB
  unsigned short* resh = (unsigned short*)(ws + T1_BYTES + QH_BYTES); // colpass..norm (48 MiB)
  // h1 aliases t1h region (dead before rowpass writes it):
  unsigned* h1 = (unsigned*)ws;
  char* tail = ws + 2 * T1_BYTES + QH_BYTES;
  float*          Dir = (float*)tail;                               // 2048 B
  unsigned short* CmH = (unsigned short*)(tail + 2048);             // 512 KB
  char* tail2 = tail + 2048 + 524288;
  float*  med  = (float*)tail2;                                     // 512 B slot
  float2* prm  = (float2*)(tail2 + 512);                            // 768 B

  k_dir<<<512, 256, 0, stream>>>(fmap_in, Dir);
  k_cmat<<<512, 256, 0, stream>>>(Dir, CmH);

  // single-pass 12-bit radix histogram + interpolated median (err ~1e-4)
  hipMemsetAsync(h1, 0, (size_t)NIMG * 4096 * 4, stream);
  k_p1<<<NIMG * 8, 256, 0, stream>>>(x, h1);
  k_med12<<<NIMG, 256, 0, stream>>>(h1, med);

  hipMemsetAsync(qh, 0, QH_BYTES, stream);
  k_rowpass<<<1536, 512, 0, stream>>>(x, mask, med, CmH, t1h);
  k_colpass<<<1536, 512, 0, stream>>>(t1h, CmH, resh, qh);

  k_pct<<<NIMG, 256, 0, stream>>>(qh, prm);
  k_norm<<<2048, 256, 0, stream>>>(resh, mask, prm, out);
}

// Round 17
// 195.911 us; speedup vs baseline: 1.3364x; 1.1045x over previous
//
#include <hip/hip_runtime.h>
#include <math.h>

#define HW 262144     // 512*512
#define NIMG 96       // B*C
#define NQBIN 4096

typedef __attribute__((ext_vector_type(8))) short bf16x8;
typedef __attribute__((ext_vector_type(4))) float f32x4;

// ---- helpers ----
__device__ __forceinline__ unsigned fmap_u(float f){
  unsigned u = __float_as_uint(f);
  return (u & 0x80000000u) ? ~u : (u | 0x80000000u);
}
__device__ __forceinline__ float funmap_u(unsigned u){
  unsigned v = (u & 0x80000000u) ? (u & 0x7fffffffu) : ~u;
  return __uint_as_float(v);
}
__device__ __forceinline__ unsigned bf16rne(float f){
  unsigned u = __float_as_uint(f);
  return (u + 0x7fffu + ((u >> 16) & 1u)) >> 16;
}

// global -> LDS direct DMA, 16 B per lane. LDS dest = wave-uniform base + lane*16.
typedef __attribute__((address_space(3))) unsigned lds_u;
typedef const __attribute__((address_space(1))) unsigned glb_u;
__device__ __forceinline__ void gll16(const void* g, void* l){
  __builtin_amdgcn_global_load_lds((glb_u*)g, (lds_u*)l, 16, 0, 0);
}

// ---- Dir[n] = Re( ifft(filter_map row 0) )[n], computed in double ----
__global__ void k_dir(const float* __restrict__ fmap_in, float* __restrict__ Dir){
  int n = blockIdx.x;
  int t = threadIdx.x;
  double s = 0.0;
  for(int c = t; c < 512; c += 256){
    int a = (c * n) & 511;
    s += (double)fmap_in[c] * cos(6.283185307179586476925287 * (double)a / 512.0);
  }
  __shared__ double red[256];
  red[t] = s; __syncthreads();
  for(int off = 128; off; off >>= 1){
    if(t < off) red[t] += red[t + off];
    __syncthreads();
  }
  if(t == 0) Dir[n] = (float)(red[0] / 512.0);
}

// ---- Cm[a][b] = bf16( Dir[(a-b)&511] )  (512 KB, L2-resident) ----
__global__ void k_cmat(const float* __restrict__ Dir, unsigned short* __restrict__ CmH){
  int a = blockIdx.x;
  for(int b = threadIdx.x; b < 512; b += 256){
    float d = Dir[(a - b) & 511];
    CmH[(size_t)a * 512 + b] = (unsigned short)bf16rne(d);
  }
}

// ==== median via single 12-bit radix histogram + in-bin interpolation ====
__global__ __launch_bounds__(256) void k_p1(const float* __restrict__ x, unsigned* __restrict__ h){
  __shared__ unsigned sh[2][4112];   // dual sub-histogram, bank-offset copy
  const int img  = blockIdx.x >> 3;
  const int part = blockIdx.x & 7;
  const int par  = threadIdx.x & 1;
  const float4* p = (const float4*)(x + (size_t)img * HW + (size_t)part * 32768);
  for(int i = threadIdx.x; i < 4112; i += 256){ sh[0][i] = 0; sh[1][i] = 0; }
  __syncthreads();
  unsigned* mine = sh[par];
  for(int i = threadIdx.x; i < 8192; i += 256){
    float4 v = p[i];
    atomicAdd(&mine[fmap_u(v.x) >> 20], 1u);
    atomicAdd(&mine[fmap_u(v.y) >> 20], 1u);
    atomicAdd(&mine[fmap_u(v.z) >> 20], 1u);
    atomicAdd(&mine[fmap_u(v.w) >> 20], 1u);
  }
  __syncthreads();
  unsigned* hh = h + (size_t)img * 4096;
  for(int i = threadIdx.x; i < 4096; i += 256){
    unsigned c = sh[0][i] + sh[1][i];
    if(c) atomicAdd(&hh[i], c);
  }
}

// scan + interpolate: med error ~1e-4 abs for N(0,1) (negligible vs bin granularity)
__global__ void k_med12(const unsigned* __restrict__ h, float* __restrict__ med){
  int img = blockIdx.x, t = threadIdx.x;
  const unsigned* hh = h + (size_t)img * 4096;
  __shared__ unsigned csum[256];
  unsigned s = 0;
  for(int j = 0; j < 16; j++) s += hh[t * 16 + j];
  csum[t] = s; __syncthreads();
  if(t == 0){
    unsigned k = 131071u, cum = 0; int chunk = 0;
    for(; chunk < 256; ++chunk){ if(cum + csum[chunk] > k) break; cum += csum[chunk]; }
    int b = chunk * 16;
    unsigned c;
    for(;; ++b){ c = hh[b]; if(cum + c > k) break; cum += c; }
    float frac = ((float)(k - cum) + 0.5f) / (float)c;
    unsigned m = ((unsigned)b << 20) + (unsigned)(frac * 1048576.0f);
    med[img] = funmap_u(m) + 0.2f;
  }
}

// ---- prepad: xh[img][h][k] = bf16( mask ? x : med[img] ) — hoists pad+convert ----
__global__ __launch_bounds__(256) void k_prepad(
    const float* __restrict__ x, const float* __restrict__ mask,
    const float* __restrict__ med, unsigned short* __restrict__ xh)
{
  size_t u8 = (size_t)blockIdx.x * 256 + threadIdx.x;   // unit = 8 elements
  size_t i  = u8 * 8;
  int img = (int)(i >> 18);
  size_t mi = ((size_t)(img / 3) << 18) + (i & 0x3FFFFu);
  const float mv = med[img];
  unsigned hp[4];
  #pragma unroll
  for(int q = 0; q < 2; q++){
    float4 xv = *(const float4*)(x + i + q * 4);
    float4 mk = *(const float4*)(mask + mi + q * 4);
    unsigned h0 = bf16rne((mk.x != 0.f) ? xv.x : mv);
    unsigned h1 = bf16rne((mk.y != 0.f) ? xv.y : mv);
    unsigned h2 = bf16rne((mk.z != 0.f) ? xv.z : mv);
    unsigned h3 = bf16rne((mk.w != 0.f) ? xv.w : mv);
    hp[q*2]   = (h1 << 16) | h0;
    hp[q*2+1] = (h3 << 16) | h2;
  }
  *(uint4*)(xh + i) = make_uint4(hp[0], hp[1], hp[2], hp[3]);
}

// ==== MFMA row pass: pure-DMA 2-operand (xh + CmH), 64 KB LDS, 2 blk/CU ====
// t1T[img][n][h] = bf16( sum_k xh[r][k] * Cm[n][k] )
__global__ __launch_bounds__(512, 4) void k_rowpass(
    const unsigned short* __restrict__ xh,
    const unsigned short* __restrict__ CmH,
    unsigned short* __restrict__ t1h)
{
  __shared__ __align__(16) unsigned short As [2][8192];
  __shared__ __align__(16) unsigned short BsH[2][8192];

  // XCD swizzle: 4 sibling n-blocks (same xh rows) on the same XCD
  const int b    = blockIdx.x;           // 0..1535
  const int xcd  = b & 7;
  const int i8   = b >> 3;
  const int rblk = xcd * 48 + (i8 >> 2);
  const int nblk = i8 & 3;
  const int r0 = rblk * 128;
  const int n0 = nblk * 128;

  const int t    = threadIdx.x;
  const int lane = t & 63;
  const int wv   = t >> 6;
  const int wm   = (wv >> 2) * 64;
  const int wn   = (wv & 3) * 32;
  const int fr   = lane & 15;
  const int fg   = lane >> 4;
  const int sw   = lane & 7;

  const int drow = lane >> 3;
  const int dblk = (lane & 7) ^ drow;
  const unsigned short* asrc  = xh  + ((size_t)(r0 + wv*8 + drow) << 9) + dblk * 8;
  const unsigned short* bhsrc = CmH + ((size_t)(n0 + wv*8 + drow) << 9) + dblk * 8;
  const int dbase = wv * 8 * 64;

  f32x4 acc[4][2];
  #pragma unroll
  for(int i = 0; i < 4; i++)
    #pragma unroll
    for(int j = 0; j < 2; j++) acc[i][j] = (f32x4){0.f, 0.f, 0.f, 0.f};

  auto STAGE = [&](int buf, int k0){
    #pragma unroll
    for(int q = 0; q < 2; q++){
      const size_t so = ((size_t)(q * 64) << 9) + k0;
      const int    dq = dbase + q * 4096;
      gll16(asrc  + so, &As [buf][dq]);
      gll16(bhsrc + so, &BsH[buf][dq]);
    }
  };
  auto COMPUTE = [&](int buf){
    bf16x8 af[4][2], bh[2][2];
    #pragma unroll
    for(int i = 0; i < 4; i++)
      #pragma unroll
      for(int kq = 0; kq < 2; kq++){
        int row = wm + i*16 + fr;
        af[i][kq] = *(const bf16x8*)&As[buf][row*64 + (((kq*4 + fg) ^ sw) << 3)];
      }
    #pragma unroll
    for(int j = 0; j < 2; j++)
      #pragma unroll
      for(int kq = 0; kq < 2; kq++){
        int row = wn + j*16 + fr;
        bh[j][kq] = *(const bf16x8*)&BsH[buf][row*64 + (((kq*4 + fg) ^ sw) << 3)];
      }
    __builtin_amdgcn_s_setprio(1);
    #pragma unroll
    for(int i = 0; i < 4; i++)
      #pragma unroll
      for(int j = 0; j < 2; j++){
        acc[i][j] = __builtin_amdgcn_mfma_f32_16x16x32_bf16(af[i][0], bh[j][0], acc[i][j], 0, 0, 0);
        acc[i][j] = __builtin_amdgcn_mfma_f32_16x16x32_bf16(af[i][1], bh[j][1], acc[i][j], 0, 0, 0);
      }
    __builtin_amdgcn_s_setprio(0);
  };

  STAGE(0, 0);
  asm volatile("s_waitcnt vmcnt(0)" ::: "memory");
  __builtin_amdgcn_s_barrier();
  #pragma unroll
  for(int it = 0; it < 7; ++it){
    STAGE((it + 1) & 1, (it + 1) * 64);
    asm volatile("s_waitcnt vmcnt(4)" ::: "memory");   // drain tile it, keep it+1 in flight
    __builtin_amdgcn_s_barrier();
    COMPUTE(it & 1);
    asm volatile("" ::: "memory");
    __builtin_amdgcn_s_barrier();
  }
  asm volatile("s_waitcnt vmcnt(0)" ::: "memory");
  __builtin_amdgcn_s_barrier();
  COMPUTE(1);

  // epilogue: t1 transposed single bf16
  const int img = r0 >> 9;
  const int hb  = r0 & 511;
  #pragma unroll
  for(int i = 0; i < 4; i++)
    #pragma unroll
    for(int j = 0; j < 2; j++){
      f32x4 a = acc[i][j];
      unsigned b0 = bf16rne(a[0]), b1 = bf16rne(a[1]), b2 = bf16rne(a[2]), b3 = bf16rne(a[3]);
      int n = n0 + wn + j*16 + fr;
      int h = hb + wm + i*16 + fg*4;
      *(uint2*)&t1h[(size_t)img * HW + ((size_t)n << 9) + h] =
          make_uint2((b1<<16)|b0, (b3<<16)|b2);
    }
}

// ==== MFMA col pass: res stored as bf16; fused q-hist ====
__global__ __launch_bounds__(512, 4) void k_colpass(
    const unsigned short* __restrict__ t1h,
    const unsigned short* __restrict__ CmH,
    unsigned short* __restrict__ resh, unsigned* __restrict__ qh)
{
  __shared__ __align__(16) unsigned short AsH[2][8192];
  __shared__ __align__(16) unsigned short Bs [2][8192];

  const int b    = blockIdx.x;           // 0..1535
  const int xcd  = b & 7;
  const int i8   = b >> 3;
  const int img  = xcd * 12 + (i8 >> 4);
  const int r16  = i8 & 15;
  const int hp0  = (r16 >> 2) * 128;
  const int w0   = (r16 & 3) * 128;

  const int t    = threadIdx.x;
  const int lane = t & 63;
  const int wv   = t >> 6;
  const int wm   = (wv >> 2) * 64;
  const int wn   = (wv & 3) * 32;
  const int fr   = lane & 15;
  const int fg   = lane >> 4;
  const int sw   = lane & 7;

  const int drow = lane >> 3;
  const int dblk = (lane & 7) ^ drow;
  const unsigned short* ahsrc = CmH + ((size_t)(hp0 + wv*8 + drow) << 9) + dblk * 8;
  const unsigned short* bsrc  = t1h + (size_t)img * HW + ((size_t)(w0 + wv*8 + drow) << 9) + dblk * 8;
  const int dbase = wv * 8 * 64;

  f32x4 acc[4][2];
  #pragma unroll
  for(int i = 0; i < 4; i++)
    #pragma unroll
    for(int j = 0; j < 2; j++) acc[i][j] = (f32x4){0.f, 0.f, 0.f, 0.f};

  auto STAGE = [&](int buf, int k0){
    #pragma unroll
    for(int q = 0; q < 2; q++){
      const size_t so = ((size_t)(q * 64) << 9) + k0;
      const int    dq = dbase + q * 4096;
      gll16(ahsrc + so, &AsH[buf][dq]);
      gll16(bsrc  + so, &Bs [buf][dq]);
    }
  };
  auto COMPUTE = [&](int buf){
    bf16x8 ah[4][2], bv[2][2];
    #pragma unroll
    for(int i = 0; i < 4; i++)
      #pragma unroll
      for(int kq = 0; kq < 2; kq++){
        int row = wm + i*16 + fr;
        ah[i][kq] = *(const bf16x8*)&AsH[buf][row*64 + (((kq*4 + fg) ^ sw) << 3)];
      }
    #pragma unroll
    for(int j = 0; j < 2; j++)
      #pragma unroll
      for(int kq = 0; kq < 2; kq++){
        int row = wn + j*16 + fr;
        bv[j][kq] = *(const bf16x8*)&Bs[buf][row*64 + (((kq*4 + fg) ^ sw) << 3)];
      }
    __builtin_amdgcn_s_setprio(1);
    #pragma unroll
    for(int i = 0; i < 4; i++)
      #pragma unroll
      for(int j = 0; j < 2; j++){
        acc[i][j] = __builtin_amdgcn_mfma_f32_16x16x32_bf16(ah[i][0], bv[j][0], acc[i][j], 0, 0, 0);
        acc[i][j] = __builtin_amdgcn_mfma_f32_16x16x32_bf16(ah[i][1], bv[j][1], acc[i][j], 0, 0, 0);
      }
    __builtin_amdgcn_s_setprio(0);
  };

  STAGE(0, 0);
  asm volatile("s_waitcnt vmcnt(0)" ::: "memory");
  __builtin_amdgcn_s_barrier();
  #pragma unroll
  for(int it = 0; it < 7; ++it){
    STAGE((it + 1) & 1, (it + 1) * 64);
    asm volatile("s_waitcnt vmcnt(4)" ::: "memory");
    __builtin_amdgcn_s_barrier();
    COMPUTE(it & 1);
    asm volatile("" ::: "memory");
    __builtin_amdgcn_s_barrier();
  }
  asm volatile("s_waitcnt vmcnt(0)" ::: "memory");
  __builtin_amdgcn_s_barrier();
  COMPUTE(1);

  // epilogue: store bf16 |acc| + LDS histogram (fp32 values), flush
  __syncthreads();
  unsigned* shh = (unsigned*)&AsH[0][0];
  for(int i = t; i < NQBIN; i += 512) shh[i] = 0;
  __syncthreads();

  unsigned short* rimg = resh + (size_t)img * HW;
  #pragma unroll
  for(int i = 0; i < 4; i++)
    #pragma unroll
    for(int j = 0; j < 2; j++){
      f32x4 a = acc[i][j];
      int w  = w0 + wn + j*16 + fr;
      int hp = hp0 + wm + i*16 + fg*4;
      #pragma unroll
      for(int r = 0; r < 4; r++){
        float v = fabsf(a[r]);
        rimg[((size_t)(hp + r) << 9) + w] = (unsigned short)bf16rne(v);
        atomicAdd(&shh[min((int)(v * 256.f), NQBIN - 1)], 1u);
      }
    }
  __syncthreads();

  unsigned* hg = qh + (size_t)img * NQBIN;
  for(int i = t; i < NQBIN; i += 512){
    unsigned c = shh[i];
    if(c) atomicAdd(&hg[i], c);
  }
}

// ---- percentiles (linear interp at 3% / 97%) -> (lo, 1/(hi-lo)) ----
__global__ void k_pct(const unsigned* __restrict__ qh, float2* __restrict__ prm){
  int img = blockIdx.x, t = threadIdx.x;
  const unsigned* h = qh + (size_t)img * NQBIN;
  __shared__ unsigned sh[NQBIN];
  for(int i = t; i < NQBIN; i += 256) sh[i] = h[i];
  __syncthreads();
  if(t == 0){
    const unsigned targ[4] = {7864u, 7865u, 254278u, 254279u};
    float v[4]; unsigned cum = 0; int b = 0;
    for(int q = 0; q < 4; q++){
      while(cum + sh[b] <= targ[q]){ cum += sh[b]; ++b; }
      v[q] = (float)b * (1.0f / 256.0f);
    }
    double plo = 0.03 * 262143.0;
    double phi = 0.97 * 262143.0;
    float lo = v[0] + (float)(plo - 7864.0)   * (v[1] - v[0]);
    float hi = v[2] + (float)(phi - 254278.0) * (v[3] - v[2]);
    prm[img] = make_float2(lo, 1.0f / (hi - lo));
  }
}

// ---- normalize: out = (bf16res - lo) * inv * mask  (bf16 in, fp32 out) ----
__global__ __launch_bounds__(256) void k_norm(const unsigned short* __restrict__ resh,
                                              const float* __restrict__ mask,
                                              const float2* __restrict__ prm,
                                              float* __restrict__ out){
  size_t i8 = (size_t)blockIdx.x * blockDim.x + threadIdx.x;
  const size_t total8 = (size_t)NIMG * HW / 8;
  const size_t step = (size_t)gridDim.x * blockDim.x;
  for(; i8 < total8; i8 += step){
    size_t i = i8 * 8;
    int bc = (int)(i >> 18);
    int bb = bc / 3;
    size_t mi = ((size_t)bb << 18) + (i & 0x3FFFFu);
    uint4 rv = *(const uint4*)(resh + i);
    float4 m0 = *(const float4*)(mask + mi);
    float4 m1 = *(const float4*)(mask + mi + 4);
    float2 p = prm[bc];
    float4 o0, o1;
    o0.x = (__uint_as_float((rv.x & 0xFFFFu) << 16) - p.x) * p.y * m0.x;
    o0.y = (__uint_as_float((rv.x & 0xFFFF0000u))   - p.x) * p.y * m0.y;
    o0.z = (__uint_as_float((rv.y & 0xFFFFu) << 16) - p.x) * p.y * m0.z;
    o0.w = (__uint_as_float((rv.y & 0xFFFF0000u))   - p.x) * p.y * m0.w;
    o1.x = (__uint_as_float((rv.z & 0xFFFFu) << 16) - p.x) * p.y * m1.x;
    o1.y = (__uint_as_float((rv.z & 0xFFFF0000u))   - p.x) * p.y * m1.y;
    o1.z = (__uint_as_float((rv.w & 0xFFFFu) << 16) - p.x) * p.y * m1.z;
    o1.w = (__uint_as_float((rv.w & 0xFFFF0000u))   - p.x) * p.y * m1.w;
    *(float4*)(out + i)     = o0;
    *(float4*)(out + i + 4) = o1;
  }
}

extern "C" void kernel_launch(void* const* d_in, const int* in_sizes, int n_in,
                              void* d_out, int out_size, void* d_ws, size_t ws_size,
                              hipStream_t stream)
{
  const float* x       = (const float*)d_in[0];
  const float* mask    = (const float*)d_in[1];
  const float* fmap_in = (const float*)d_in[2];
  float* out = (float*)d_out;

  const size_t T1_BYTES = (size_t)NIMG * HW * 2;   // 48 MiB
  const size_t QH_BYTES = (size_t)NIMG * NQBIN * 4;
  char* ws = (char*)d_ws;
  unsigned short* t1h  = (unsigned short*)ws;                         // rowpass..colpass
  unsigned*       qh   = (unsigned*)(ws + T1_BYTES);                  // 1.5 MB
  // xh (prepad..rowpass) and resh (colpass..norm) have disjoint lifetimes -> share:
  unsigned short* xh   = (unsigned short*)(ws + T1_BYTES + QH_BYTES); // 48 MiB
  unsigned short* resh = xh;
  // h1 aliases t1h region (dead before rowpass writes it):
  unsigned* h1 = (unsigned*)ws;
  char* tail = ws + 2 * T1_BYTES + QH_BYTES;
  float*          Dir = (float*)tail;                                 // 2048 B
  unsigned short* CmH = (unsigned short*)(tail + 2048);               // 512 KB
  char* tail2 = tail + 2048 + 524288;
  float*  med  = (float*)tail2;                                       // 512 B slot
  float2* prm  = (float2*)(tail2 + 512);                              // 768 B

  k_dir<<<512, 256, 0, stream>>>(fmap_in, Dir);
  k_cmat<<<512, 256, 0, stream>>>(Dir, CmH);

  // single-pass 12-bit radix histogram + interpolated median (err ~1e-4)
  hipMemsetAsync(h1, 0, (size_t)NIMG * 4096 * 4, stream);
  k_p1<<<NIMG * 8, 256, 0, stream>>>(x, h1);
  k_med12<<<NIMG, 256, 0, stream>>>(h1, med);

  // pad+convert once; both GEMM passes become pure-DMA staging
  k_prepad<<<(NIMG * HW / 8) / 256, 256, 0, stream>>>(x, mask, med, xh);

  hipMemsetAsync(qh, 0, QH_BYTES, stream);
  k_rowpass<<<1536, 512, 0, stream>>>(xh, CmH, t1h);
  k_colpass<<<1536, 512, 0, stream>>>(t1h, CmH, resh, qh);

  k_pct<<<NIMG, 256, 0, stream>>>(qh, prm);
  k_norm<<<2048, 256, 0, stream>>>(resh, mask, prm, out);
}

// Round 18
// 190.373 us; speedup vs baseline: 1.3753x; 1.0291x over previous
//
#include <hip/hip_runtime.h>
#include <math.h>

#define HW 262144     // 512*512
#define NIMG 96       // B*C
#define NQBIN 4096

typedef __attribute__((ext_vector_type(8))) short bf16x8;
typedef __attribute__((ext_vector_type(4))) float f32x4;

// ---- helpers ----
__device__ __forceinline__ unsigned fmap_u(float f){
  unsigned u = __float_as_uint(f);
  return (u & 0x80000000u) ? ~u : (u | 0x80000000u);
}
__device__ __forceinline__ float funmap_u(unsigned u){
  unsigned v = (u & 0x80000000u) ? (u & 0x7fffffffu) : ~u;
  return __uint_as_float(v);
}
__device__ __forceinline__ unsigned bf16rne(float f){
  unsigned u = __float_as_uint(f);
  return (u + 0x7fffu + ((u >> 16) & 1u)) >> 16;
}

// global -> LDS direct DMA, 16 B per lane. LDS dest = wave-uniform base + lane*16.
typedef __attribute__((address_space(3))) unsigned lds_u;
typedef const __attribute__((address_space(1))) unsigned glb_u;
__device__ __forceinline__ void gll16(const void* g, void* l){
  __builtin_amdgcn_global_load_lds((glb_u*)g, (lds_u*)l, 16, 0, 0);
}

// ---- Dir[n] = Re( ifft(filter_map row 0) )[n], computed in double ----
__global__ void k_dir(const float* __restrict__ fmap_in, float* __restrict__ Dir){
  int n = blockIdx.x;
  int t = threadIdx.x;
  double s = 0.0;
  for(int c = t; c < 512; c += 256){
    int a = (c * n) & 511;
    s += (double)fmap_in[c] * cos(6.283185307179586476925287 * (double)a / 512.0);
  }
  __shared__ double red[256];
  red[t] = s; __syncthreads();
  for(int off = 128; off; off >>= 1){
    if(t < off) red[t] += red[t + off];
    __syncthreads();
  }
  if(t == 0) Dir[n] = (float)(red[0] / 512.0);
}

// ---- Cm[a][b] = bf16( Dir[(a-b)&511] ) + zero h1 (replaces hipMemsetAsync) ----
__global__ void k_cmat(const float* __restrict__ Dir, unsigned short* __restrict__ CmH,
                       unsigned* __restrict__ h1){
  int a = blockIdx.x;
  for(int b = threadIdx.x; b < 512; b += 256){
    float d = Dir[(a - b) & 511];
    CmH[(size_t)a * 512 + b] = (unsigned short)bf16rne(d);
  }
  // zero h1: 96*4096 = 393216 words over 512*256 = 131072 threads (3 each)
  unsigned idx = blockIdx.x * 256 + threadIdx.x;
  #pragma unroll
  for(int j = 0; j < 3; j++) h1[idx + j * 131072u] = 0;
}

// ==== median via single 12-bit radix histogram + in-bin interpolation ====
__global__ __launch_bounds__(256) void k_p1(const float* __restrict__ x, unsigned* __restrict__ h){
  __shared__ unsigned sh[2][4112];   // dual sub-histogram, bank-offset copy
  const int img  = blockIdx.x >> 3;
  const int part = blockIdx.x & 7;
  const int par  = threadIdx.x & 1;
  const float4* p = (const float4*)(x + (size_t)img * HW + (size_t)part * 32768);
  for(int i = threadIdx.x; i < 4112; i += 256){ sh[0][i] = 0; sh[1][i] = 0; }
  __syncthreads();
  unsigned* mine = sh[par];
  for(int i = threadIdx.x; i < 8192; i += 256){
    float4 v = p[i];
    atomicAdd(&mine[fmap_u(v.x) >> 20], 1u);
    atomicAdd(&mine[fmap_u(v.y) >> 20], 1u);
    atomicAdd(&mine[fmap_u(v.z) >> 20], 1u);
    atomicAdd(&mine[fmap_u(v.w) >> 20], 1u);
  }
  __syncthreads();
  unsigned* hh = h + (size_t)img * 4096;
  for(int i = threadIdx.x; i < 4096; i += 256){
    unsigned c = sh[0][i] + sh[1][i];
    if(c) atomicAdd(&hh[i], c);
  }
}

// scan + interpolate: med error ~1e-4 abs for N(0,1) (negligible vs bin granularity)
__global__ void k_med12(const unsigned* __restrict__ h, float* __restrict__ med){
  int img = blockIdx.x, t = threadIdx.x;
  const unsigned* hh = h + (size_t)img * 4096;
  __shared__ unsigned csum[256];
  unsigned s = 0;
  for(int j = 0; j < 16; j++) s += hh[t * 16 + j];
  csum[t] = s; __syncthreads();
  if(t == 0){
    unsigned k = 131071u, cum = 0; int chunk = 0;
    for(; chunk < 256; ++chunk){ if(cum + csum[chunk] > k) break; cum += csum[chunk]; }
    int b = chunk * 16;
    unsigned c;
    for(;; ++b){ c = hh[b]; if(cum + c > k) break; cum += c; }
    float frac = ((float)(k - cum) + 0.5f) / (float)c;
    unsigned m = ((unsigned)b << 20) + (unsigned)(frac * 1048576.0f);
    med[img] = funmap_u(m) + 0.2f;
  }
}

// ---- prepad: xh = bf16(mask?x:med) + zero qh (replaces hipMemsetAsync) ----
__global__ __launch_bounds__(256) void k_prepad(
    const float* __restrict__ x, const float* __restrict__ mask,
    const float* __restrict__ med, unsigned short* __restrict__ xh,
    unsigned* __restrict__ qh)
{
  size_t u8 = (size_t)blockIdx.x * 256 + threadIdx.x;   // unit = 8 elements
  if(u8 < (size_t)NIMG * NQBIN) qh[u8] = 0;             // 393216 words zeroed
  size_t i  = u8 * 8;
  int img = (int)(i >> 18);
  size_t mi = ((size_t)(img / 3) << 18) + (i & 0x3FFFFu);
  const float mv = med[img];
  unsigned hp[4];
  #pragma unroll
  for(int q = 0; q < 2; q++){
    float4 xv = *(const float4*)(x + i + q * 4);
    float4 mk = *(const float4*)(mask + mi + q * 4);
    unsigned h0 = bf16rne((mk.x != 0.f) ? xv.x : mv);
    unsigned h1 = bf16rne((mk.y != 0.f) ? xv.y : mv);
    unsigned h2 = bf16rne((mk.z != 0.f) ? xv.z : mv);
    unsigned h3 = bf16rne((mk.w != 0.f) ? xv.w : mv);
    hp[q*2]   = (h1 << 16) | h0;
    hp[q*2+1] = (h3 << 16) | h2;
  }
  *(uint4*)(xh + i) = make_uint4(hp[0], hp[1], hp[2], hp[3]);
}

// ==== MFMA row pass: pure-DMA 2-operand (xh + CmH), 64 KB LDS, 2 blk/CU ====
// t1T[img][n][h] = bf16( sum_k xh[r][k] * Cm[n][k] )
__global__ __launch_bounds__(512, 4) void k_rowpass(
    const unsigned short* __restrict__ xh,
    const unsigned short* __restrict__ CmH,
    unsigned short* __restrict__ t1h)
{
  __shared__ __align__(16) unsigned short As [2][8192];
  __shared__ __align__(16) unsigned short BsH[2][8192];

  // XCD swizzle: 4 sibling n-blocks (same xh rows) on the same XCD
  const int b    = blockIdx.x;           // 0..1535
  const int xcd  = b & 7;
  const int i8   = b >> 3;
  const int rblk = xcd * 48 + (i8 >> 2);
  const int nblk = i8 & 3;
  const int r0 = rblk * 128;
  const int n0 = nblk * 128;

  const int t    = threadIdx.x;
  const int lane = t & 63;
  const int wv   = t >> 6;
  const int wm   = (wv >> 2) * 64;
  const int wn   = (wv & 3) * 32;
  const int fr   = lane & 15;
  const int fg   = lane >> 4;
  const int sw   = lane & 7;

  const int drow = lane >> 3;
  const int dblk = (lane & 7) ^ drow;
  const unsigned short* asrc  = xh  + ((size_t)(r0 + wv*8 + drow) << 9) + dblk * 8;
  const unsigned short* bhsrc = CmH + ((size_t)(n0 + wv*8 + drow) << 9) + dblk * 8;
  const int dbase = wv * 8 * 64;

  f32x4 acc[4][2];
  #pragma unroll
  for(int i = 0; i < 4; i++)
    #pragma unroll
    for(int j = 0; j < 2; j++) acc[i][j] = (f32x4){0.f, 0.f, 0.f, 0.f};

  auto STAGE = [&](int buf, int k0){
    #pragma unroll
    for(int q = 0; q < 2; q++){
      const size_t so = ((size_t)(q * 64) << 9) + k0;
      const int    dq = dbase + q * 4096;
      gll16(asrc  + so, &As [buf][dq]);
      gll16(bhsrc + so, &BsH[buf][dq]);
    }
  };
  auto COMPUTE = [&](int buf){
    bf16x8 af[4][2], bh[2][2];
    #pragma unroll
    for(int i = 0; i < 4; i++)
      #pragma unroll
      for(int kq = 0; kq < 2; kq++){
        int row = wm + i*16 + fr;
        af[i][kq] = *(const bf16x8*)&As[buf][row*64 + (((kq*4 + fg) ^ sw) << 3)];
      }
    #pragma unroll
    for(int j = 0; j < 2; j++)
      #pragma unroll
      for(int kq = 0; kq < 2; kq++){
        int row = wn + j*16 + fr;
        bh[j][kq] = *(const bf16x8*)&BsH[buf][row*64 + (((kq*4 + fg) ^ sw) << 3)];
      }
    __builtin_amdgcn_s_setprio(1);
    #pragma unroll
    for(int i = 0; i < 4; i++)
      #pragma unroll
      for(int j = 0; j < 2; j++){
        acc[i][j] = __builtin_amdgcn_mfma_f32_16x16x32_bf16(af[i][0], bh[j][0], acc[i][j], 0, 0, 0);
        acc[i][j] = __builtin_amdgcn_mfma_f32_16x16x32_bf16(af[i][1], bh[j][1], acc[i][j], 0, 0, 0);
      }
    __builtin_amdgcn_s_setprio(0);
  };

  STAGE(0, 0);
  asm volatile("s_waitcnt vmcnt(0)" ::: "memory");
  __builtin_amdgcn_s_barrier();
  #pragma unroll
  for(int it = 0; it < 7; ++it){
    STAGE((it + 1) & 1, (it + 1) * 64);
    asm volatile("s_waitcnt vmcnt(4)" ::: "memory");   // drain tile it, keep it+1 in flight
    __builtin_amdgcn_s_barrier();
    COMPUTE(it & 1);
    asm volatile("" ::: "memory");
    __builtin_amdgcn_s_barrier();
  }
  asm volatile("s_waitcnt vmcnt(0)" ::: "memory");
  __builtin_amdgcn_s_barrier();
  COMPUTE(1);

  // epilogue: t1 transposed single bf16
  const int img = r0 >> 9;
  const int hb  = r0 & 511;
  #pragma unroll
  for(int i = 0; i < 4; i++)
    #pragma unroll
    for(int j = 0; j < 2; j++){
      f32x4 a = acc[i][j];
      unsigned b0 = bf16rne(a[0]), b1 = bf16rne(a[1]), b2 = bf16rne(a[2]), b3 = bf16rne(a[3]);
      int n = n0 + wn + j*16 + fr;
      int h = hb + wm + i*16 + fg*4;
      *(uint2*)&t1h[(size_t)img * HW + ((size_t)n << 9) + h] =
          make_uint2((b1<<16)|b0, (b3<<16)|b2);
    }
}

// ==== MFMA col pass: res stored as bf16; fused q-hist ====
__global__ __launch_bounds__(512, 4) void k_colpass(
    const unsigned short* __restrict__ t1h,
    const unsigned short* __restrict__ CmH,
    unsigned short* __restrict__ resh, unsigned* __restrict__ qh)
{
  __shared__ __align__(16) unsigned short AsH[2][8192];
  __shared__ __align__(16) unsigned short Bs [2][8192];

  const int b    = blockIdx.x;           // 0..1535
  const int xcd  = b & 7;
  const int i8   = b >> 3;
  const int img  = xcd * 12 + (i8 >> 4);
  const int r16  = i8 & 15;
  const int hp0  = (r16 >> 2) * 128;
  const int w0   = (r16 & 3) * 128;

  const int t    = threadIdx.x;
  const int lane = t & 63;
  const int wv   = t >> 6;
  const int wm   = (wv >> 2) * 64;
  const int wn   = (wv & 3) * 32;
  const int fr   = lane & 15;
  const int fg   = lane >> 4;
  const int sw   = lane & 7;

  const int drow = lane >> 3;
  const int dblk = (lane & 7) ^ drow;
  const unsigned short* ahsrc = CmH + ((size_t)(hp0 + wv*8 + drow) << 9) + dblk * 8;
  const unsigned short* bsrc  = t1h + (size_t)img * HW + ((size_t)(w0 + wv*8 + drow) << 9) + dblk * 8;
  const int dbase = wv * 8 * 64;

  f32x4 acc[4][2];
  #pragma unroll
  for(int i = 0; i < 4; i++)
    #pragma unroll
    for(int j = 0; j < 2; j++) acc[i][j] = (f32x4){0.f, 0.f, 0.f, 0.f};

  auto STAGE = [&](int buf, int k0){
    #pragma unroll
    for(int q = 0; q < 2; q++){
      const size_t so = ((size_t)(q * 64) << 9) + k0;
      const int    dq = dbase + q * 4096;
      gll16(ahsrc + so, &AsH[buf][dq]);
      gll16(bsrc  + so, &Bs [buf][dq]);
    }
  };
  auto COMPUTE = [&](int buf){
    bf16x8 ah[4][2], bv[2][2];
    #pragma unroll
    for(int i = 0; i < 4; i++)
      #pragma unroll
      for(int kq = 0; kq < 2; kq++){
        int row = wm + i*16 + fr;
        ah[i][kq] = *(const bf16x8*)&AsH[buf][row*64 + (((kq*4 + fg) ^ sw) << 3)];
      }
    #pragma unroll
    for(int j = 0; j < 2; j++)
      #pragma unroll
      for(int kq = 0; kq < 2; kq++){
        int row = wn + j*16 + fr;
        bv[j][kq] = *(const bf16x8*)&Bs[buf][row*64 + (((kq*4 + fg) ^ sw) << 3)];
      }
    __builtin_amdgcn_s_setprio(1);
    #pragma unroll
    for(int i = 0; i < 4; i++)
      #pragma unroll
      for(int j = 0; j < 2; j++){
        acc[i][j] = __builtin_amdgcn_mfma_f32_16x16x32_bf16(ah[i][0], bv[j][0], acc[i][j], 0, 0, 0);
        acc[i][j] = __builtin_amdgcn_mfma_f32_16x16x32_bf16(ah[i][1], bv[j][1], acc[i][j], 0, 0, 0);
      }
    __builtin_amdgcn_s_setprio(0);
  };

  STAGE(0, 0);
  asm volatile("s_waitcnt vmcnt(0)" ::: "memory");
  __builtin_amdgcn_s_barrier();
  #pragma unroll
  for(int it = 0; it < 7; ++it){
    STAGE((it + 1) & 1, (it + 1) * 64);
    asm volatile("s_waitcnt vmcnt(4)" ::: "memory");
    __builtin_amdgcn_s_barrier();
    COMPUTE(it & 1);
    asm volatile("" ::: "memory");
    __builtin_amdgcn_s_barrier();
  }
  asm volatile("s_waitcnt vmcnt(0)" ::: "memory");
  __builtin_amdgcn_s_barrier();
  COMPUTE(1);

  // epilogue: store bf16 |acc| + LDS histogram (fp32 values), flush
  __syncthreads();
  unsigned* shh = (unsigned*)&AsH[0][0];
  for(int i = t; i < NQBIN; i += 512) shh[i] = 0;
  __syncthreads();

  unsigned short* rimg = resh + (size_t)img * HW;
  #pragma unroll
  for(int i = 0; i < 4; i++)
    #pragma unroll
    for(int j = 0; j < 2; j++){
      f32x4 a = acc[i][j];
      int w  = w0 + wn + j*16 + fr;
      int hp = hp0 + wm + i*16 + fg*4;
      #pragma unroll
      for(int r = 0; r < 4; r++){
        float v = fabsf(a[r]);
        rimg[((size_t)(hp + r) << 9) + w] = (unsigned short)bf16rne(v);
        atomicAdd(&shh[min((int)(v * 256.f), NQBIN - 1)], 1u);
      }
    }
  __syncthreads();

  unsigned* hg = qh + (size_t)img * NQBIN;
  for(int i = t; i < NQBIN; i += 512){
    unsigned c = shh[i];
    if(c) atomicAdd(&hg[i], c);
  }
}

// ---- percentiles (linear interp at 3% / 97%) -> (lo, 1/(hi-lo)) ----
__global__ void k_pct(const unsigned* __restrict__ qh, float2* __restrict__ prm){
  int img = blockIdx.x, t = threadIdx.x;
  const unsigned* h = qh + (size_t)img * NQBIN;
  __shared__ unsigned sh[NQBIN];
  for(int i = t; i < NQBIN; i += 256) sh[i] = h[i];
  __syncthreads();
  if(t == 0){
    const unsigned targ[4] = {7864u, 7865u, 254278u, 254279u};
    float v[4]; unsigned cum = 0; int b = 0;
    for(int q = 0; q < 4; q++){
      while(cum + sh[b] <= targ[q]){ cum += sh[b]; ++b; }
      v[q] = (float)b * (1.0f / 256.0f);
    }
    double plo = 0.03 * 262143.0;
    double phi = 0.97 * 262143.0;
    float lo = v[0] + (float)(plo - 7864.0)   * (v[1] - v[0]);
    float hi = v[2] + (float)(phi - 254278.0) * (v[3] - v[2]);
    prm[img] = make_float2(lo, 1.0f / (hi - lo));
  }
}

// ---- normalize: out = (bf16res - lo) * inv * mask  (bf16 in, fp32 out) ----
__global__ __launch_bounds__(256) void k_norm(const unsigned short* __restrict__ resh,
                                              const float* __restrict__ mask,
                                              const float2* __restrict__ prm,
                                              float* __restrict__ out){
  size_t i8 = (size_t)blockIdx.x * blockDim.x + threadIdx.x;
  const size_t total8 = (size_t)NIMG * HW / 8;
  const size_t step = (size_t)gridDim.x * blockDim.x;
  for(; i8 < total8; i8 += step){
    size_t i = i8 * 8;
    int bc = (int)(i >> 18);
    int bb = bc / 3;
    size_t mi = ((size_t)bb << 18) + (i & 0x3FFFFu);
    uint4 rv = *(const uint4*)(resh + i);
    float4 m0 = *(const float4*)(mask + mi);
    float4 m1 = *(const float4*)(mask + mi + 4);
    float2 p = prm[bc];
    float4 o0, o1;
    o0.x = (__uint_as_float((rv.x & 0xFFFFu) << 16) - p.x) * p.y * m0.x;
    o0.y = (__uint_as_float((rv.x & 0xFFFF0000u))   - p.x) * p.y * m0.y;
    o0.z = (__uint_as_float((rv.y & 0xFFFFu) << 16) - p.x) * p.y * m0.z;
    o0.w = (__uint_as_float((rv.y & 0xFFFF0000u))   - p.x) * p.y * m0.w;
    o1.x = (__uint_as_float((rv.z & 0xFFFFu) << 16) - p.x) * p.y * m1.x;
    o1.y = (__uint_as_float((rv.z & 0xFFFF0000u))   - p.x) * p.y * m1.y;
    o1.z = (__uint_as_float((rv.w & 0xFFFFu) << 16) - p.x) * p.y * m1.z;
    o1.w = (__uint_as_float((rv.w & 0xFFFF0000u))   - p.x) * p.y * m1.w;
    *(float4*)(out + i)     = o0;
    *(float4*)(out + i + 4) = o1;
  }
}

extern "C" void kernel_launch(void* const* d_in, const int* in_sizes, int n_in,
                              void* d_out, int out_size, void* d_ws, size_t ws_size,
                              hipStream_t stream)
{
  const float* x       = (const float*)d_in[0];
  const float* mask    = (const float*)d_in[1];
  const float* fmap_in = (const float*)d_in[2];
  float* out = (float*)d_out;

  const size_t T1_BYTES = (size_t)NIMG * HW * 2;   // 48 MiB
  const size_t QH_BYTES = (size_t)NIMG * NQBIN * 4;
  char* ws = (char*)d_ws;
  unsigned short* t1h  = (unsigned short*)ws;                         // rowpass..colpass
  unsigned*       qh   = (unsigned*)(ws + T1_BYTES);                  // 1.5 MB
  // xh (prepad..rowpass) and resh (colpass..norm) have disjoint lifetimes -> share:
  unsigned short* xh   = (unsigned short*)(ws + T1_BYTES + QH_BYTES); // 48 MiB
  unsigned short* resh = xh;
  // h1 aliases t1h region (dead before rowpass writes it):
  unsigned* h1 = (unsigned*)ws;
  char* tail = ws + 2 * T1_BYTES + QH_BYTES;
  float*          Dir = (float*)tail;                                 // 2048 B
  unsigned short* CmH = (unsigned short*)(tail + 2048);               // 512 KB
  char* tail2 = tail + 2048 + 524288;
  float*  med  = (float*)tail2;                                       // 512 B slot
  float2* prm  = (float2*)(tail2 + 512);                              // 768 B

  k_dir<<<512, 256, 0, stream>>>(fmap_in, Dir);
  k_cmat<<<512, 256, 0, stream>>>(Dir, CmH, h1);     // also zeroes h1

  // single-pass 12-bit radix histogram + interpolated median (err ~1e-4)
  k_p1<<<NIMG * 8, 256, 0, stream>>>(x, h1);
  k_med12<<<NIMG, 256, 0, stream>>>(h1, med);

  // pad+convert once (also zeroes qh); both GEMM passes become pure-DMA staging
  k_prepad<<<(NIMG * HW / 8) / 256, 256, 0, stream>>>(x, mask, med, xh, qh);

  k_rowpass<<<1536, 512, 0, stream>>>(xh, CmH, t1h);
  k_colpass<<<1536, 512, 0, stream>>>(t1h, CmH, resh, qh);

  k_pct<<<NIMG, 256, 0, stream>>>(qh, prm);
  k_norm<<<2048, 256, 0, stream>>>(resh, mask, prm, out);
}